// Round 10
// baseline (1549.609 us; speedup 1.0000x reference)
//
#include <hip/hip_runtime.h>
#include <hip/hip_cooperative_groups.h>
#include <math.h>

namespace cgx = cooperative_groups;

#define B_ 2
#define C_ 256
#define L_ 4096
#define BL_ 8192
#define DEPTH_ 4
#define CK_ 64   // chunks per sequence
#define CL_ 64   // chunk length

typedef __attribute__((ext_vector_type(8))) short bf16x8;
typedef __attribute__((ext_vector_type(4))) float f32x4;
#define MFMA16 __builtin_amdgcn_mfma_f32_16x16x32_bf16

__device__ __forceinline__ float silu_(float x){ return x/(1.f+__expf(-x)); }
__device__ __forceinline__ float softplus_(float x){ return fmaxf(x,0.f)+log1pf(__expf(-fabsf(x))); }
__device__ __forceinline__ unsigned short f2b_(float f){
    union{float f;unsigned u;}v; v.f=f;
    unsigned r=(v.u + 0x7fffu + ((v.u>>16)&1u))>>16;
    return (unsigned short)r;
}

// ---------------- fp32 -> bf16 weight conversion ----------------
__global__ __launch_bounds__(256) void k_w2b(const float* __restrict__ src, unsigned short* __restrict__ dst)
{
    int i=blockIdx.x*256+threadIdx.x;
    float4 v=((const float4*)src)[i];
    ushort4 o; o.x=f2b_(v.x); o.y=f2b_(v.y); o.z=f2b_(v.z); o.w=f2b_(v.w);
    ((ushort4*)dst)[i]=o;
}

// ---------------- composed dt weight: W_eff[i][c][k] = sum_j dt_w[i][c][j]*xw[i][j][k] -> bf16 ----------------
__global__ __launch_bounds__(256) void k_wdt(
    const float* __restrict__ dtw, const float* __restrict__ xw,
    unsigned short* __restrict__ wdtb)
{
    int blk=blockIdx.x;          // i*256 + c
    int i=blk>>8, c=blk&255, k=threadIdx.x;
    const float* dr=dtw+((size_t)i*C_+c)*16;
    const float* xr=xw+(size_t)i*48*C_+k;
    float acc=0.f;
    #pragma unroll
    for(int j=0;j<16;j++) acc=fmaf(dr[j], xr[(size_t)j*C_], acc);
    wdtb[((size_t)i*C_+c)*C_+k]=f2b_(acc);
}

// ---------------- transpose in: x (B,C,D,H,W) -> t [B][L][C], l=(h*16+w)*16+d ----------------
__global__ __launch_bounds__(256) void k_t_in(const float* __restrict__ x, float* __restrict__ t)
{
    __shared__ float tile[16*257];
    int blk=blockIdx.x, b=blk>>8, d=(blk>>4)&15, h=blk&15;
    int tid=threadIdx.x;
    int w2=tid&15;
    for(int p=0;p<16;p++){
        int c=(tid>>4)+16*p;
        tile[w2*257+c]=x[((size_t)(b*C_+c))*4096 + d*256 + h*16 + w2];
    }
    __syncthreads();
    for(int k=0;k<16;k++){
        t[((size_t)b*L_+(h*16+k)*16+d)*C_+tid]=tile[k*257+tid];
    }
}

// ---------------- LN1: t -> hb (bf16 [M][256]) ----------------
__global__ __launch_bounds__(256) void k_ln(
    const float* __restrict__ t, const float* __restrict__ g,
    const float* __restrict__ be, unsigned short* __restrict__ hb)
{
    int wv=threadIdx.x>>6, lane=threadIdx.x&63;
    int row=blockIdx.x*4+wv;
    float4 v=((const float4*)(t+(size_t)row*C_))[lane];
    float s=v.x+v.y+v.z+v.w;
    float ss=v.x*v.x+v.y*v.y+v.z*v.z+v.w*v.w;
    #pragma unroll
    for(int m=1;m<64;m<<=1){ s+=__shfl_xor(s,m); ss+=__shfl_xor(ss,m); }
    float mn=s*(1.f/256.f);
    float rs=rsqrtf(ss*(1.f/256.f)-mn*mn+1e-5f);
    float4 gg=((const float4*)g)[lane];
    float4 bb=((const float4*)be)[lane];
    ushort4 o;
    o.x=f2b_((v.x-mn)*rs*gg.x+bb.x);
    o.y=f2b_((v.y-mn)*rs*gg.y+bb.y);
    o.z=f2b_((v.z-mn)*rs*gg.z+bb.z);
    o.w=f2b_((v.w-mn)*rs*gg.w+bb.w);
    ((ushort4*)(hb+(size_t)row*C_))[lane]=o;
}

// ---------------- MFMA GEMM: xs|z[m][n] = hb[m][k] * Wt[n][k] ; N=512 split ----------------
__global__ __launch_bounds__(256) void k_gemm_in(
    const unsigned short* __restrict__ Ab, const unsigned short* __restrict__ Wb,
    float* __restrict__ xs, float* __restrict__ z)
{
    int wv=threadIdx.x>>6, lane=threadIdx.x&63;
    int m0=blockIdx.x*64+(wv>>1)*32;
    int n0=blockIdx.y*64+(wv&1)*32;
    int la=lane&15, kg=lane>>4;
    f32x4 acc[2][2];
    #pragma unroll
    for(int i=0;i<2;i++)
        #pragma unroll
        for(int j=0;j<2;j++) acc[i][j]=(f32x4){0.f,0.f,0.f,0.f};
    const unsigned short* a0p=Ab+(size_t)(m0+la)*C_+kg*8;
    const unsigned short* a1p=Ab+(size_t)(m0+16+la)*C_+kg*8;
    const unsigned short* b0p=Wb+(size_t)(n0+la)*C_+kg*8;
    const unsigned short* b1p=Wb+(size_t)(n0+16+la)*C_+kg*8;
    #pragma unroll
    for(int kk=0;kk<C_;kk+=32){
        bf16x8 a0=*(const bf16x8*)(a0p+kk);
        bf16x8 a1=*(const bf16x8*)(a1p+kk);
        bf16x8 b0=*(const bf16x8*)(b0p+kk);
        bf16x8 b1=*(const bf16x8*)(b1p+kk);
        acc[0][0]=MFMA16(a0,b0,acc[0][0],0,0,0);
        acc[0][1]=MFMA16(a0,b1,acc[0][1],0,0,0);
        acc[1][0]=MFMA16(a1,b0,acc[1][0],0,0,0);
        acc[1][1]=MFMA16(a1,b1,acc[1][1],0,0,0);
    }
    #pragma unroll
    for(int mi=0;mi<2;mi++)
        #pragma unroll
        for(int nj=0;nj<2;nj++)
            #pragma unroll
            for(int r=0;r<4;r++){
                int m=m0+mi*16+kg*4+r;
                int n=n0+nj*16+la;
                float val=acc[mi][nj][r];
                if(n<256) xs[(size_t)m*C_+n]=val;
                else      z [(size_t)m*C_+(n-256)]=val;
            }
}

// ---------------- MFMA GEMM + residual: t[m][n] += y2b[m][k] * Wt[n][k] ----------------
__global__ __launch_bounds__(256) void k_gemm_out(
    const unsigned short* __restrict__ Ab, const unsigned short* __restrict__ Wb,
    float* __restrict__ t)
{
    int wv=threadIdx.x>>6, lane=threadIdx.x&63;
    int m0=blockIdx.x*64+(wv>>1)*32;
    int n0=blockIdx.y*64+(wv&1)*32;
    int la=lane&15, kg=lane>>4;
    f32x4 acc[2][2];
    #pragma unroll
    for(int i=0;i<2;i++)
        #pragma unroll
        for(int j=0;j<2;j++) acc[i][j]=(f32x4){0.f,0.f,0.f,0.f};
    const unsigned short* a0p=Ab+(size_t)(m0+la)*C_+kg*8;
    const unsigned short* a1p=Ab+(size_t)(m0+16+la)*C_+kg*8;
    const unsigned short* b0p=Wb+(size_t)(n0+la)*C_+kg*8;
    const unsigned short* b1p=Wb+(size_t)(n0+16+la)*C_+kg*8;
    #pragma unroll
    for(int kk=0;kk<C_;kk+=32){
        bf16x8 a0=*(const bf16x8*)(a0p+kk);
        bf16x8 a1=*(const bf16x8*)(a1p+kk);
        bf16x8 b0=*(const bf16x8*)(b0p+kk);
        bf16x8 b1=*(const bf16x8*)(b1p+kk);
        acc[0][0]=MFMA16(a0,b0,acc[0][0],0,0,0);
        acc[0][1]=MFMA16(a0,b1,acc[0][1],0,0,0);
        acc[1][0]=MFMA16(a1,b0,acc[1][0],0,0,0);
        acc[1][1]=MFMA16(a1,b1,acc[1][1],0,0,0);
    }
    #pragma unroll
    for(int mi=0;mi<2;mi++)
        #pragma unroll
        for(int nj=0;nj<2;nj++)
            #pragma unroll
            for(int r=0;r<4;r++){
                int m=m0+mi*16+kg*4+r;
                int n=n0+nj*16+la;
                float* tp=t+(size_t)m*C_+n;
                *tp=*tp+acc[mi][nj][r];
            }
}

// ---------------- MFMA GEMM: BC[m][0:32] = seqb[m][k] * xwb[16+n][k] ----------------
__global__ __launch_bounds__(256) void k_gemm_x(
    const unsigned short* __restrict__ Ab, const unsigned short* __restrict__ Wb,
    float* __restrict__ BC)
{
    int wv=threadIdx.x>>6, lane=threadIdx.x&63;
    int m0=blockIdx.x*128+wv*32;
    int la=lane&15, kg=lane>>4;
    f32x4 acc[2][2];
    #pragma unroll
    for(int i=0;i<2;i++)
        #pragma unroll
        for(int j=0;j<2;j++) acc[i][j]=(f32x4){0.f,0.f,0.f,0.f};
    const unsigned short* a0p=Ab+(size_t)(m0+la)*C_+kg*8;
    const unsigned short* a1p=Ab+(size_t)(m0+16+la)*C_+kg*8;
    const unsigned short* b0p=Wb+(size_t)(16+la)*C_+kg*8;   // B rows of xproj_w
    const unsigned short* b1p=Wb+(size_t)(32+la)*C_+kg*8;   // C rows
    #pragma unroll
    for(int kk=0;kk<C_;kk+=32){
        bf16x8 a0=*(const bf16x8*)(a0p+kk);
        bf16x8 a1=*(const bf16x8*)(a1p+kk);
        bf16x8 b0=*(const bf16x8*)(b0p+kk);
        bf16x8 b1=*(const bf16x8*)(b1p+kk);
        acc[0][0]=MFMA16(a0,b0,acc[0][0],0,0,0);
        acc[0][1]=MFMA16(a0,b1,acc[0][1],0,0,0);
        acc[1][0]=MFMA16(a1,b0,acc[1][0],0,0,0);
        acc[1][1]=MFMA16(a1,b1,acc[1][1],0,0,0);
    }
    #pragma unroll
    for(int mi=0;mi<2;mi++)
        #pragma unroll
        for(int nj=0;nj<2;nj++)
            #pragma unroll
            for(int r=0;r<4;r++){
                int m=m0+mi*16+kg*4+r;
                BC[(size_t)m*32 + nj*16+la]=acc[mi][nj][r];
            }
}

// ---------------- MFMA GEMM: dt[m][c] = softplus(seqb[m][k]*wdtb[c][k] + dt_b[c]) ----------------
__global__ __launch_bounds__(256) void k_gemm_dt(
    const unsigned short* __restrict__ Ab, const unsigned short* __restrict__ Wb,
    const float* __restrict__ dtbias, float* __restrict__ dt)
{
    int wv=threadIdx.x>>6, lane=threadIdx.x&63;
    int m0=blockIdx.x*64+(wv>>1)*32;
    int n0=blockIdx.y*64+(wv&1)*32;
    int la=lane&15, kg=lane>>4;
    f32x4 acc[2][2];
    #pragma unroll
    for(int i=0;i<2;i++)
        #pragma unroll
        for(int j=0;j<2;j++) acc[i][j]=(f32x4){0.f,0.f,0.f,0.f};
    const unsigned short* a0p=Ab+(size_t)(m0+la)*C_+kg*8;
    const unsigned short* a1p=Ab+(size_t)(m0+16+la)*C_+kg*8;
    const unsigned short* b0p=Wb+(size_t)(n0+la)*C_+kg*8;
    const unsigned short* b1p=Wb+(size_t)(n0+16+la)*C_+kg*8;
    #pragma unroll
    for(int kk=0;kk<C_;kk+=32){
        bf16x8 a0=*(const bf16x8*)(a0p+kk);
        bf16x8 a1=*(const bf16x8*)(a1p+kk);
        bf16x8 b0=*(const bf16x8*)(b0p+kk);
        bf16x8 b1=*(const bf16x8*)(b1p+kk);
        acc[0][0]=MFMA16(a0,b0,acc[0][0],0,0,0);
        acc[0][1]=MFMA16(a0,b1,acc[0][1],0,0,0);
        acc[1][0]=MFMA16(a1,b0,acc[1][0],0,0,0);
        acc[1][1]=MFMA16(a1,b1,acc[1][1],0,0,0);
    }
    float bias0=dtbias[n0+la], bias1=dtbias[n0+16+la];
    #pragma unroll
    for(int mi=0;mi<2;mi++)
        #pragma unroll
        for(int nj=0;nj<2;nj++)
            #pragma unroll
            for(int r=0;r<4;r++){
                int m=m0+mi*16+kg*4+r;
                int n=n0+nj*16+la;
                float val=acc[mi][nj][r]+((nj==0)?bias0:bias1);
                dt[(size_t)m*C_+n]=softplus_(val);
            }
}

// ---------------- depthwise conv3x3x3, register-blocked along d ----------------
__global__ __launch_bounds__(256) void k_conv(
    const float* __restrict__ xs, const float* __restrict__ cw,
    const float* __restrict__ cb, float* __restrict__ seq,
    unsigned short* __restrict__ seqb, int ori)
{
    __shared__ float wl[256*27];
    int tid=threadIdx.x;
    for(int j=tid;j<256*27;j+=256) wl[j]=cw[j];
    int blk=blockIdx.x;          // b*256 + h*16 + w
    int b=blk>>8, h=(blk>>4)&15, w=blk&15;
    __syncthreads();
    const float* wp=wl+tid*27;
    float bias=cb[tid];
    float acc[16];
    #pragma unroll
    for(int d=0;d<16;d++) acc[d]=bias;
    #pragma unroll
    for(int kh=0;kh<3;kh++){
        int hh=h+kh-1; if((unsigned)hh>=16u) continue;
        #pragma unroll
        for(int kw=0;kw<3;kw++){
            int ww=w+kw-1; if((unsigned)ww>=16u) continue;
            const float* bp=xs+((size_t)(b*L_)+(hh*16+ww)*16)*C_+tid;
            float w0=wp[(kh*3+kw)*3+0];
            float w1=wp[(kh*3+kw)*3+1];
            float w2=wp[(kh*3+kw)*3+2];
            #pragma unroll
            for(int dd=0;dd<16;dd++){
                float v=bp[(size_t)dd*C_];
                if(dd<15) acc[dd+1]=fmaf(w0,v,acc[dd+1]);
                acc[dd]=fmaf(w1,v,acc[dd]);
                if(dd>0)  acc[dd-1]=fmaf(w2,v,acc[dd-1]);
            }
        }
    }
    int hf=(ori&1)?15-h:h;
    int wf=(ori&2)?15-w:w;
    size_t obase=((size_t)b*L_+(hf*16+wf)*16)*C_+tid;
    #pragma unroll
    for(int d=0;d<16;d++){
        float a=silu_(acc[d]);
        int df=(ori&4)?15-d:d;
        size_t oidx=obase+(size_t)df*C_;
        seq[oidx]=a;
        seqb[oidx]=f2b_(a);
    }
}

// ---------------- fused cooperative selective scan ----------------
// 1024 blocks x 256 thr (4 blocks/CU, all co-resident). Block owns 16 channels x 2 chunks,
// both chunk tiles persistent in LDS across phases. A: local scans (2-way ILP).
// B: 8192-thread chunk chain. C: replay purely from LDS, y staged via LDS tile.
__global__ __launch_bounds__(256,4) void k_scan_fused(
    const float* __restrict__ seqx, const float* __restrict__ dtlc,
    const float* __restrict__ BC, const float* __restrict__ A_log,
    const float* __restrict__ Dsk,
    float* __restrict__ Ap, float* __restrict__ Ho, float* __restrict__ Sb,
    float* __restrict__ y)
{
    __shared__ float2 dxL[2][64][17];   // (dt,x); reused as y tile at the end
    __shared__ float  bcL[2][64][32];
    int tid=threadIdx.x;
    int blk=blockIdx.x;
    int cgi=blk>>5, ck0=(blk&31)*2;
    int p0=cgi*16, b=p0>>8, c0=p0&255;
    int wv=tid>>6, lane=tid&63, grp=lane>>4, n=lane&15;
    int cl=wv*4+grp, pair=p0+cl, c=c0+cl;
    float An=-__expf(A_log[c*16+n]);
    int lr=tid>>2, c4=tid&3, o8=(tid&3)*8;
    // ---- load both chunk tiles (coalesced float4 rows) ----
    #pragma unroll
    for(int q2=0;q2<2;q2++){
        int l0=(ck0+q2)*CL_;
        size_t base=((size_t)(b*L_+l0+lr))*C_+c0+c4*4;
        float4 x4=*(const float4*)(seqx+base);
        float4 d4=*(const float4*)(dtlc+base);
        dxL[q2][lr][c4*4+0]=make_float2(d4.x,x4.x);
        dxL[q2][lr][c4*4+1]=make_float2(d4.y,x4.y);
        dxL[q2][lr][c4*4+2]=make_float2(d4.z,x4.z);
        dxL[q2][lr][c4*4+3]=make_float2(d4.w,x4.w);
        const float* bs=BC+((size_t)(b*L_+l0+lr))*32+o8;
        float4 bv0=*(const float4*)bs, bv1=*(const float4*)(bs+4);
        *(float4*)&bcL[q2][lr][o8]=bv0;
        *(float4*)&bcL[q2][lr][o8+4]=bv1;
    }
    __syncthreads();
    // ---- phase A: local scans, two independent recurrence chains ----
    {
        float cA=0.f,cB=0.f,sA=0.f,sB=0.f;
        #pragma unroll 8
        for(int l=0;l<CL_;l++){
            float2 dxa=dxL[0][l][cl]; float bva=bcL[0][l][n];
            float2 dxb=dxL[1][l][cl]; float bvb=bcL[1][l][n];
            float dAa=__expf(dxa.x*An), dAb=__expf(dxb.x*An);
            cA=fmaf(dAa,cA,dxa.x*bva*dxa.y);
            cB=fmaf(dAb,cB,dxb.x*bvb*dxb.y);
            sA+=dxa.x; sB+=dxb.x;
        }
        int ia=(pair*CK_+ck0)*16+n;
        Ap[ia]=__expf(An*sA);    Ho[ia]=cA;
        Ap[ia+16]=__expf(An*sB); Ho[ia+16]=cB;
    }
    cgx::this_grid().sync();
    // ---- phase B: serial chain over chunk summaries ----
    {
        int gid=blk*256+tid;
        if(gid<8192){
            int pr=gid>>4, nn=gid&15;
            float S=0.f;
            #pragma unroll
            for(int ck=0;ck<CK_;ck++){
                int idx=(pr*CK_+ck)*16+nn;
                Sb[idx]=S;
                S=fmaf(Ap[idx],S,Ho[idx]);
            }
        }
    }
    cgx::this_grid().sync();
    // ---- phase C: replay with carry-in, purely from LDS ----
    float Dc=Dsk[c];
    float yrA[4], yrB[4];
    {
        float cA=Sb[(pair*CK_+ck0)*16+n];
        float cB=Sb[(pair*CK_+ck0+1)*16+n];
        #pragma unroll
        for(int q=0;q<4;q++){
            #pragma unroll 4
            for(int l2=0;l2<16;l2++){
                int l=q*16+l2;
                float2 dxa=dxL[0][l][cl]; float bva=bcL[0][l][n], cva=bcL[0][l][16+n];
                float2 dxb=dxL[1][l][cl]; float bvb=bcL[1][l][n], cvb=bcL[1][l][16+n];
                float dAa=__expf(dxa.x*An), dAb=__expf(dxb.x*An);
                cA=fmaf(dAa,cA,dxa.x*bva*dxa.y);
                cB=fmaf(dAb,cB,dxb.x*bvb*dxb.y);
                float pa=cA*cva, pb=cB*cvb;
                pa+=__shfl_xor(pa,1); pb+=__shfl_xor(pb,1);
                pa+=__shfl_xor(pa,2); pb+=__shfl_xor(pb,2);
                pa+=__shfl_xor(pa,4); pb+=__shfl_xor(pb,4);
                pa+=__shfl_xor(pa,8); pb+=__shfl_xor(pb,8);
                float ya=fmaf(Dc,dxa.y,pa), yb=fmaf(Dc,dxb.y,pb);
                if(l2==n){ yrA[q]=ya; yrB[q]=yb; }
            }
        }
    }
    __syncthreads();            // all waves done reading dxL
    float* yT0=(float*)&dxL[0][0][0];
    float* yT1=(float*)&dxL[1][0][0];
    #pragma unroll
    for(int q=0;q<4;q++){
        int l=q*16+n;
        yT0[l*17+cl]=yrA[q];
        yT1[l*17+cl]=yrB[q];
    }
    __syncthreads();
    #pragma unroll
    for(int q2=0;q2<2;q2++){
        const float* yT=(q2==0)?yT0:yT1;
        int l0=(ck0+q2)*CL_;
        size_t base=((size_t)(b*L_+l0+lr))*C_+c0+c4*4;
        float4 o=make_float4(yT[lr*17+c4*4+0],yT[lr*17+c4*4+1],
                             yT[lr*17+c4*4+2],yT[lr*17+c4*4+3]);
        *(float4*)(y+base)=o;
    }
}

// ---------------- unflip + out-LN + gate by SiLU(z) -> y2b (bf16) ----------------
__global__ __launch_bounds__(256) void k_post(
    const float* __restrict__ y, const float* __restrict__ z,
    const float* __restrict__ og, const float* __restrict__ ob,
    unsigned short* __restrict__ y2b, int ori)
{
    __shared__ float red[8];
    int c=threadIdx.x;
    int bl=blockIdx.x, b=bl>>12, l=bl&4095;
    int d=l&15, w=(l>>4)&15, h=l>>8;
    int hf=(ori&1)?15-h:h, wf=(ori&2)?15-w:w, df=(ori&4)?15-d:d;
    int lf=(hf*16+wf)*16+df;
    float v=y[((size_t)b*L_+lf)*C_+c];
    float s=v, ss=v*v;
    #pragma unroll
    for(int m=32;m>=1;m>>=1){ s+=__shfl_xor(s,m); ss+=__shfl_xor(ss,m); }
    if((c&63)==0){ red[(c>>6)*2]=s; red[(c>>6)*2+1]=ss; }
    __syncthreads();
    s=red[0]+red[2]+red[4]+red[6];
    ss=red[1]+red[3]+red[5]+red[7];
    float mn=s*(1.f/256.f);
    float rstd=rsqrtf(ss*(1.f/256.f)-mn*mn+1e-5f);
    float yn=(v-mn)*rstd*og[c]+ob[c];
    float zv=z[((size_t)b*L_+l)*C_+c];
    y2b[((size_t)b*L_+l)*C_+c]=f2b_(yn*silu_(zv));
}

// ---------------- final LN + transpose out ----------------
__global__ __launch_bounds__(256) void k_final(
    const float* __restrict__ t, const float* __restrict__ pg,
    const float* __restrict__ pb, float* __restrict__ out)
{
    __shared__ float tile[16*257];
    __shared__ float mrs[16][2];
    int blk=blockIdx.x, b=blk>>8, d=(blk>>4)&15, h=blk&15;
    int tid=threadIdx.x;
    for(int w2=0;w2<16;w2++){
        tile[w2*257+tid]=t[((size_t)b*L_+(h*16+w2)*16+d)*C_+tid];
    }
    __syncthreads();
    int r=tid>>4, p=tid&15;
    float s=0.f, ss=0.f;
    #pragma unroll
    for(int k=0;k<16;k++){ float v=tile[r*257+k*16+p]; s+=v; ss+=v*v; }
    #pragma unroll
    for(int m=1;m<16;m<<=1){ s+=__shfl_xor(s,m); ss+=__shfl_xor(ss,m); }
    if(p==0){ float mn=s*(1.f/256.f); mrs[r][0]=mn; mrs[r][1]=rsqrtf(ss*(1.f/256.f)-mn*mn+1e-5f); }
    __syncthreads();
    int w2=tid&15;
    for(int p2=0;p2<16;p2++){
        int c=(tid>>4)+16*p2;
        float v=tile[w2*257+c];
        float vn=(v-mrs[w2][0])*mrs[w2][1]*pg[c]+pb[c];
        out[((size_t)(b*C_+c))*4096 + d*256 + h*16 + w2]=vn;
    }
}

extern "C" void kernel_launch(void* const* d_in, const int* in_sizes, int n_in,
                              void* d_out, int out_size, void* d_ws, size_t ws_size,
                              hipStream_t stream)
{
    (void)in_sizes; (void)n_in; (void)out_size; (void)ws_size;
    const float* x      =(const float*)d_in[0];
    const float* in_w   =(const float*)d_in[1];
    const float* conv_w =(const float*)d_in[2];
    const float* conv_b =(const float*)d_in[3];
    const float* xproj_w=(const float*)d_in[4];
    const float* dt_w   =(const float*)d_in[5];
    const float* dt_b   =(const float*)d_in[6];
    const float* A_log  =(const float*)d_in[7];
    const float* D_skip =(const float*)d_in[8];
    const float* on_g   =(const float*)d_in[9];
    const float* on_b   =(const float*)d_in[10];
    const float* out_w  =(const float*)d_in[11];
    const float* ln1_g  =(const float*)d_in[12];
    const float* ln1_b  =(const float*)d_in[13];
    const float* post_g =(const float*)d_in[14];
    const float* post_b =(const float*)d_in[15];
    float* out=(float*)d_out;
    float* ws=(float*)d_ws;

    const size_t NBL=(size_t)BL_*C_;     // 2,097,152 elems
    float* t    = ws;                     // residual stream [B][L][C]
    float* xs   = ws +   NBL;             // conv input; reused as dtlc after conv
    float* z    = ws + 2*NBL;
    float* seq  = ws + 3*NBL;             // conv output [l][c] fp32; scan writes y in-place
    float* BC   = ws + 4*NBL;             // [B*L][32] fp32 (Bm | Cm)
    float* Ap   = BC + (size_t)BL_*32;
    float* Ho   = Ap + 512*CK_*16;
    float* Sb   = Ho + 512*CK_*16;
    unsigned short* hb   = (unsigned short*)(Sb + 512*CK_*16);  // bf16 LN'd activations
    unsigned short* seqb = hb   + NBL;                          // bf16 conv output
    unsigned short* y2b  = seqb + NBL;                          // bf16 gated output
    unsigned short* wbI  = y2b  + NBL;                          // bf16 in_w  (4*512*256)
    unsigned short* wbO  = wbI + (size_t)DEPTH_*512*C_;         // bf16 out_w (4*256*256)
    unsigned short* xwb  = wbO + (size_t)DEPTH_*C_*C_;          // bf16 xproj_w (4*48*256)
    unsigned short* wdtb = xwb + (size_t)DEPTH_*48*C_;          // bf16 W_eff (4*256*256)
    float* dtlc = xs;                     // dt[l][c] fp32 — aliases xs (dead after conv)

    k_w2b<<<DEPTH_*512*C_/1024,256,0,stream>>>(in_w, wbI);
    k_w2b<<<DEPTH_*C_*C_/1024,256,0,stream>>>(out_w, wbO);
    k_w2b<<<DEPTH_*48*C_/1024,256,0,stream>>>(xproj_w, xwb);
    k_wdt<<<DEPTH_*C_,256,0,stream>>>(dt_w, xproj_w, wdtb);
    k_t_in<<<512,256,0,stream>>>(x,t);
    for(int i=0;i<DEPTH_;i++){
        int ori=i&7;
        k_ln<<<2048,256,0,stream>>>(t, ln1_g+i*256, ln1_b+i*256, hb);
        k_gemm_in<<<dim3(128,8),256,0,stream>>>(hb, wbI+(size_t)i*512*C_, xs, z);
        k_conv<<<512,256,0,stream>>>(xs, conv_w+(size_t)i*6912, conv_b+i*256, seq, seqb, ori);
        k_gemm_x<<<64,256,0,stream>>>(seqb, xwb+(size_t)i*48*C_, BC);
        k_gemm_dt<<<dim3(128,4),256,0,stream>>>(seqb, wdtb+(size_t)i*C_*C_, dt_b+i*256, dtlc);
        {
            const float* Alp = A_log + (size_t)i*4096;
            const float* Dp  = D_skip + i*256;
            const float* seqc = seq;
            const float* dtc  = dtlc;
            const float* bcc  = BC;
            float* yp = seq;
            void* sa[9];
            sa[0]=(void*)&seqc; sa[1]=(void*)&dtc; sa[2]=(void*)&bcc;
            sa[3]=(void*)&Alp;  sa[4]=(void*)&Dp;
            sa[5]=(void*)&Ap;   sa[6]=(void*)&Ho;  sa[7]=(void*)&Sb;
            sa[8]=(void*)&yp;
            hipLaunchCooperativeKernel((void*)k_scan_fused, dim3(1024), dim3(256), sa, 0, stream);
        }
        k_post<<<8192,256,0,stream>>>(seq, z, on_g+i*256, on_b+i*256, y2b, ori);
        k_gemm_out<<<dim3(128,4),256,0,stream>>>(y2b, wbO+(size_t)i*C_*C_, t);
    }
    k_final<<<512,256,0,stream>>>(t, post_g, post_b, out);
}

// Round 11
// 519.441 us; speedup vs baseline: 2.9832x; 2.9832x over previous
//
#include <hip/hip_runtime.h>
#include <math.h>

#define B_ 2
#define C_ 256
#define L_ 4096
#define BL_ 8192
#define DEPTH_ 4
#define CK_ 64   // chunks per sequence
#define CL_ 64   // chunk length

typedef __attribute__((ext_vector_type(8))) short bf16x8;
typedef __attribute__((ext_vector_type(4))) float f32x4;
#define MFMA16 __builtin_amdgcn_mfma_f32_16x16x32_bf16

__device__ __forceinline__ float silu_(float x){ return x/(1.f+__expf(-x)); }
__device__ __forceinline__ float softplus_(float x){ return fmaxf(x,0.f)+log1pf(__expf(-fabsf(x))); }
__device__ __forceinline__ unsigned short f2b_(float f){
    union{float f;unsigned u;}v; v.f=f;
    unsigned r=(v.u + 0x7fffu + ((v.u>>16)&1u))>>16;
    return (unsigned short)r;
}

// ---------------- fp32 -> bf16 weight conversion ----------------
__global__ __launch_bounds__(256) void k_w2b(const float* __restrict__ src, unsigned short* __restrict__ dst)
{
    int i=blockIdx.x*256+threadIdx.x;
    float4 v=((const float4*)src)[i];
    ushort4 o; o.x=f2b_(v.x); o.y=f2b_(v.y); o.z=f2b_(v.z); o.w=f2b_(v.w);
    ((ushort4*)dst)[i]=o;
}

// ---------------- composed dt weight: W_eff[i][c][k] = sum_j dt_w[i][c][j]*xw[i][j][k] -> bf16 ----------------
__global__ __launch_bounds__(256) void k_wdt(
    const float* __restrict__ dtw, const float* __restrict__ xw,
    unsigned short* __restrict__ wdtb)
{
    int blk=blockIdx.x;          // i*256 + c
    int i=blk>>8, c=blk&255, k=threadIdx.x;
    const float* dr=dtw+((size_t)i*C_+c)*16;
    const float* xr=xw+(size_t)i*48*C_+k;
    float acc=0.f;
    #pragma unroll
    for(int j=0;j<16;j++) acc=fmaf(dr[j], xr[(size_t)j*C_], acc);
    wdtb[((size_t)i*C_+c)*C_+k]=f2b_(acc);
}

// ---------------- transpose in: x (B,C,D,H,W) -> t [B][L][C], l=(h*16+w)*16+d ----------------
__global__ __launch_bounds__(256) void k_t_in(const float* __restrict__ x, float* __restrict__ t)
{
    __shared__ float tile[16*257];
    int blk=blockIdx.x, b=blk>>8, d=(blk>>4)&15, h=blk&15;
    int tid=threadIdx.x;
    int w2=tid&15;
    for(int p=0;p<16;p++){
        int c=(tid>>4)+16*p;
        tile[w2*257+c]=x[((size_t)(b*C_+c))*4096 + d*256 + h*16 + w2];
    }
    __syncthreads();
    for(int k=0;k<16;k++){
        t[((size_t)b*L_+(h*16+k)*16+d)*C_+tid]=tile[k*257+tid];
    }
}

// ---------------- LN1: t -> hb (bf16 [M][256]) ----------------
__global__ __launch_bounds__(256) void k_ln(
    const float* __restrict__ t, const float* __restrict__ g,
    const float* __restrict__ be, unsigned short* __restrict__ hb)
{
    int wv=threadIdx.x>>6, lane=threadIdx.x&63;
    int row=blockIdx.x*4+wv;
    float4 v=((const float4*)(t+(size_t)row*C_))[lane];
    float s=v.x+v.y+v.z+v.w;
    float ss=v.x*v.x+v.y*v.y+v.z*v.z+v.w*v.w;
    #pragma unroll
    for(int m=1;m<64;m<<=1){ s+=__shfl_xor(s,m); ss+=__shfl_xor(ss,m); }
    float mn=s*(1.f/256.f);
    float rs=rsqrtf(ss*(1.f/256.f)-mn*mn+1e-5f);
    float4 gg=((const float4*)g)[lane];
    float4 bb=((const float4*)be)[lane];
    ushort4 o;
    o.x=f2b_((v.x-mn)*rs*gg.x+bb.x);
    o.y=f2b_((v.y-mn)*rs*gg.y+bb.y);
    o.z=f2b_((v.z-mn)*rs*gg.z+bb.z);
    o.w=f2b_((v.w-mn)*rs*gg.w+bb.w);
    ((ushort4*)(hb+(size_t)row*C_))[lane]=o;
}

// ---------------- MFMA GEMM: xs|z[m][n] = hb[m][k] * Wt[n][k] ; N=512 split ----------------
__global__ __launch_bounds__(256) void k_gemm_in(
    const unsigned short* __restrict__ Ab, const unsigned short* __restrict__ Wb,
    float* __restrict__ xs, float* __restrict__ z)
{
    int wv=threadIdx.x>>6, lane=threadIdx.x&63;
    int m0=blockIdx.x*64+(wv>>1)*32;
    int n0=blockIdx.y*64+(wv&1)*32;
    int la=lane&15, kg=lane>>4;
    f32x4 acc[2][2];
    #pragma unroll
    for(int i=0;i<2;i++)
        #pragma unroll
        for(int j=0;j<2;j++) acc[i][j]=(f32x4){0.f,0.f,0.f,0.f};
    const unsigned short* a0p=Ab+(size_t)(m0+la)*C_+kg*8;
    const unsigned short* a1p=Ab+(size_t)(m0+16+la)*C_+kg*8;
    const unsigned short* b0p=Wb+(size_t)(n0+la)*C_+kg*8;
    const unsigned short* b1p=Wb+(size_t)(n0+16+la)*C_+kg*8;
    #pragma unroll
    for(int kk=0;kk<C_;kk+=32){
        bf16x8 a0=*(const bf16x8*)(a0p+kk);
        bf16x8 a1=*(const bf16x8*)(a1p+kk);
        bf16x8 b0=*(const bf16x8*)(b0p+kk);
        bf16x8 b1=*(const bf16x8*)(b1p+kk);
        acc[0][0]=MFMA16(a0,b0,acc[0][0],0,0,0);
        acc[0][1]=MFMA16(a0,b1,acc[0][1],0,0,0);
        acc[1][0]=MFMA16(a1,b0,acc[1][0],0,0,0);
        acc[1][1]=MFMA16(a1,b1,acc[1][1],0,0,0);
    }
    #pragma unroll
    for(int mi=0;mi<2;mi++)
        #pragma unroll
        for(int nj=0;nj<2;nj++)
            #pragma unroll
            for(int r=0;r<4;r++){
                int m=m0+mi*16+kg*4+r;
                int n=n0+nj*16+la;
                float val=acc[mi][nj][r];
                if(n<256) xs[(size_t)m*C_+n]=val;
                else      z [(size_t)m*C_+(n-256)]=val;
            }
}

// ---------------- MFMA GEMM + residual: t[m][n] += y2b[m][k] * Wt[n][k] ----------------
__global__ __launch_bounds__(256) void k_gemm_out(
    const unsigned short* __restrict__ Ab, const unsigned short* __restrict__ Wb,
    float* __restrict__ t)
{
    int wv=threadIdx.x>>6, lane=threadIdx.x&63;
    int m0=blockIdx.x*64+(wv>>1)*32;
    int n0=blockIdx.y*64+(wv&1)*32;
    int la=lane&15, kg=lane>>4;
    f32x4 acc[2][2];
    #pragma unroll
    for(int i=0;i<2;i++)
        #pragma unroll
        for(int j=0;j<2;j++) acc[i][j]=(f32x4){0.f,0.f,0.f,0.f};
    const unsigned short* a0p=Ab+(size_t)(m0+la)*C_+kg*8;
    const unsigned short* a1p=Ab+(size_t)(m0+16+la)*C_+kg*8;
    const unsigned short* b0p=Wb+(size_t)(n0+la)*C_+kg*8;
    const unsigned short* b1p=Wb+(size_t)(n0+16+la)*C_+kg*8;
    #pragma unroll
    for(int kk=0;kk<C_;kk+=32){
        bf16x8 a0=*(const bf16x8*)(a0p+kk);
        bf16x8 a1=*(const bf16x8*)(a1p+kk);
        bf16x8 b0=*(const bf16x8*)(b0p+kk);
        bf16x8 b1=*(const bf16x8*)(b1p+kk);
        acc[0][0]=MFMA16(a0,b0,acc[0][0],0,0,0);
        acc[0][1]=MFMA16(a0,b1,acc[0][1],0,0,0);
        acc[1][0]=MFMA16(a1,b0,acc[1][0],0,0,0);
        acc[1][1]=MFMA16(a1,b1,acc[1][1],0,0,0);
    }
    #pragma unroll
    for(int mi=0;mi<2;mi++)
        #pragma unroll
        for(int nj=0;nj<2;nj++)
            #pragma unroll
            for(int r=0;r<4;r++){
                int m=m0+mi*16+kg*4+r;
                int n=n0+nj*16+la;
                float* tp=t+(size_t)m*C_+n;
                *tp=*tp+acc[mi][nj][r];
            }
}

// ---------------- MFMA GEMM: BC[m][0:32] = seqb[m][k] * xwb[16+n][k] ----------------
__global__ __launch_bounds__(256) void k_gemm_x(
    const unsigned short* __restrict__ Ab, const unsigned short* __restrict__ Wb,
    float* __restrict__ BC)
{
    int wv=threadIdx.x>>6, lane=threadIdx.x&63;
    int m0=blockIdx.x*128+wv*32;
    int la=lane&15, kg=lane>>4;
    f32x4 acc[2][2];
    #pragma unroll
    for(int i=0;i<2;i++)
        #pragma unroll
        for(int j=0;j<2;j++) acc[i][j]=(f32x4){0.f,0.f,0.f,0.f};
    const unsigned short* a0p=Ab+(size_t)(m0+la)*C_+kg*8;
    const unsigned short* a1p=Ab+(size_t)(m0+16+la)*C_+kg*8;
    const unsigned short* b0p=Wb+(size_t)(16+la)*C_+kg*8;   // B rows of xproj_w
    const unsigned short* b1p=Wb+(size_t)(32+la)*C_+kg*8;   // C rows
    #pragma unroll
    for(int kk=0;kk<C_;kk+=32){
        bf16x8 a0=*(const bf16x8*)(a0p+kk);
        bf16x8 a1=*(const bf16x8*)(a1p+kk);
        bf16x8 b0=*(const bf16x8*)(b0p+kk);
        bf16x8 b1=*(const bf16x8*)(b1p+kk);
        acc[0][0]=MFMA16(a0,b0,acc[0][0],0,0,0);
        acc[0][1]=MFMA16(a0,b1,acc[0][1],0,0,0);
        acc[1][0]=MFMA16(a1,b0,acc[1][0],0,0,0);
        acc[1][1]=MFMA16(a1,b1,acc[1][1],0,0,0);
    }
    #pragma unroll
    for(int mi=0;mi<2;mi++)
        #pragma unroll
        for(int nj=0;nj<2;nj++)
            #pragma unroll
            for(int r=0;r<4;r++){
                int m=m0+mi*16+kg*4+r;
                BC[(size_t)m*32 + nj*16+la]=acc[mi][nj][r];
            }
}

// ---------------- MFMA GEMM: dt[m][c] = softplus(seqb[m][k]*wdtb[c][k] + dt_b[c]) ----------------
__global__ __launch_bounds__(256) void k_gemm_dt(
    const unsigned short* __restrict__ Ab, const unsigned short* __restrict__ Wb,
    const float* __restrict__ dtbias, float* __restrict__ dt)
{
    int wv=threadIdx.x>>6, lane=threadIdx.x&63;
    int m0=blockIdx.x*64+(wv>>1)*32;
    int n0=blockIdx.y*64+(wv&1)*32;
    int la=lane&15, kg=lane>>4;
    f32x4 acc[2][2];
    #pragma unroll
    for(int i=0;i<2;i++)
        #pragma unroll
        for(int j=0;j<2;j++) acc[i][j]=(f32x4){0.f,0.f,0.f,0.f};
    const unsigned short* a0p=Ab+(size_t)(m0+la)*C_+kg*8;
    const unsigned short* a1p=Ab+(size_t)(m0+16+la)*C_+kg*8;
    const unsigned short* b0p=Wb+(size_t)(n0+la)*C_+kg*8;
    const unsigned short* b1p=Wb+(size_t)(n0+16+la)*C_+kg*8;
    #pragma unroll
    for(int kk=0;kk<C_;kk+=32){
        bf16x8 a0=*(const bf16x8*)(a0p+kk);
        bf16x8 a1=*(const bf16x8*)(a1p+kk);
        bf16x8 b0=*(const bf16x8*)(b0p+kk);
        bf16x8 b1=*(const bf16x8*)(b1p+kk);
        acc[0][0]=MFMA16(a0,b0,acc[0][0],0,0,0);
        acc[0][1]=MFMA16(a0,b1,acc[0][1],0,0,0);
        acc[1][0]=MFMA16(a1,b0,acc[1][0],0,0,0);
        acc[1][1]=MFMA16(a1,b1,acc[1][1],0,0,0);
    }
    float bias0=dtbias[n0+la], bias1=dtbias[n0+16+la];
    #pragma unroll
    for(int mi=0;mi<2;mi++)
        #pragma unroll
        for(int nj=0;nj<2;nj++)
            #pragma unroll
            for(int r=0;r<4;r++){
                int m=m0+mi*16+kg*4+r;
                int n=n0+nj*16+la;
                float val=acc[mi][nj][r]+((nj==0)?bias0:bias1);
                dt[(size_t)m*C_+n]=softplus_(val);
            }
}

// ---------------- depthwise conv3x3x3, register-blocked along d ----------------
__global__ __launch_bounds__(256) void k_conv(
    const float* __restrict__ xs, const float* __restrict__ cw,
    const float* __restrict__ cb, float* __restrict__ seq,
    unsigned short* __restrict__ seqb, int ori)
{
    __shared__ float wl[256*27];
    int tid=threadIdx.x;
    for(int j=tid;j<256*27;j+=256) wl[j]=cw[j];
    int blk=blockIdx.x;          // b*256 + h*16 + w
    int b=blk>>8, h=(blk>>4)&15, w=blk&15;
    __syncthreads();
    const float* wp=wl+tid*27;
    float bias=cb[tid];
    float acc[16];
    #pragma unroll
    for(int d=0;d<16;d++) acc[d]=bias;
    #pragma unroll
    for(int kh=0;kh<3;kh++){
        int hh=h+kh-1; if((unsigned)hh>=16u) continue;
        #pragma unroll
        for(int kw=0;kw<3;kw++){
            int ww=w+kw-1; if((unsigned)ww>=16u) continue;
            const float* bp=xs+((size_t)(b*L_)+(hh*16+ww)*16)*C_+tid;
            float w0=wp[(kh*3+kw)*3+0];
            float w1=wp[(kh*3+kw)*3+1];
            float w2=wp[(kh*3+kw)*3+2];
            #pragma unroll
            for(int dd=0;dd<16;dd++){
                float v=bp[(size_t)dd*C_];
                if(dd<15) acc[dd+1]=fmaf(w0,v,acc[dd+1]);
                acc[dd]=fmaf(w1,v,acc[dd]);
                if(dd>0)  acc[dd-1]=fmaf(w2,v,acc[dd-1]);
            }
        }
    }
    int hf=(ori&1)?15-h:h;
    int wf=(ori&2)?15-w:w;
    size_t obase=((size_t)b*L_+(hf*16+wf)*16)*C_+tid;
    #pragma unroll
    for(int d=0;d<16;d++){
        float a=silu_(acc[d]);
        int df=(ori&4)?15-d:d;
        size_t oidx=obase+(size_t)df*C_;
        seq[oidx]=a;
        seqb[oidx]=f2b_(a);
    }
}

// ---------------- chunked selective scan (corner-turn tiles) ----------------
__global__ __launch_bounds__(256) void k_scan1(
    const float* __restrict__ seqx, const float* __restrict__ dtlc,
    const float* __restrict__ BC, const float* __restrict__ A_log,
    float* __restrict__ Ap, float* __restrict__ Ho)
{
    __shared__ float2 dxL[64][17];
    int tid=threadIdx.x;
    int blk=blockIdx.x, cg=blk>>6, ck=blk&63;
    int p0=cg*16, b=p0>>8, c0=p0&255;
    int l0=ck*CL_;
    {
        int l=tid>>2, c4=tid&3;
        size_t base=((size_t)(b*L_+l0+l))*C_ + c0 + c4*4;
        float4 x4=*(const float4*)(seqx+base);
        float4 d4=*(const float4*)(dtlc+base);
        dxL[l][c4*4+0]=make_float2(d4.x,x4.x);
        dxL[l][c4*4+1]=make_float2(d4.y,x4.y);
        dxL[l][c4*4+2]=make_float2(d4.z,x4.z);
        dxL[l][c4*4+3]=make_float2(d4.w,x4.w);
    }
    __syncthreads();
    int wv=tid>>6, lane=tid&63, grp=lane>>4, n=lane&15;
    int cl=wv*4+grp, pair=p0+cl, c=c0+cl;
    float An=-__expf(A_log[c*16+n]);
    const float* bcp=BC+((size_t)(b*L_+l0))*32;
    float carry=0.f, sdt=0.f;
    #pragma unroll 8
    for(int l=0;l<CL_;l++){
        float2 dx=dxL[l][cl];
        float bv=bcp[l*32+n];
        float dA=__expf(dx.x*An);
        carry=fmaf(dA,carry,dx.x*bv*dx.y);
        sdt+=dx.x;
    }
    int idx=(pair*CK_+ck)*16+n;
    Ap[idx]=__expf(An*sdt); Ho[idx]=carry;
}

__global__ __launch_bounds__(256) void k_scan2(
    const float* __restrict__ Ap, const float* __restrict__ Ho, float* __restrict__ Sb)
{
    int gid=blockIdx.x*256+threadIdx.x;
    int pair=gid>>4, n=gid&15;
    float S=0.f;
    #pragma unroll
    for(int ck=0;ck<CK_;ck++){
        int idx=(pair*CK_+ck)*16+n;
        Sb[idx]=S;
        S=fmaf(Ap[idx],S,Ho[idx]);
    }
}

// scan3: replay with carry-in. Shuffle-free: 16-step batches buffer parts in
// registers, then a conflict-free LDS 16x16 transpose + in-register row sum
// replaces the per-step 4-deep dependent shfl chain.
__global__ __launch_bounds__(256) void k_scan3(
    const float* __restrict__ seqx, const float* __restrict__ dtlc,
    const float* __restrict__ BC, const float* __restrict__ A_log,
    const float* __restrict__ Dsk, const float* __restrict__ Sb,
    float* __restrict__ y)   // y == seqx: in-place, block regions are disjoint
{
    __shared__ float2 dxL[64][17];
    __shared__ float  bcL[64][32];
    __shared__ float  sc[16][16][17];   // [cl][l2][n+pad]; reused as y tile
    int tid=threadIdx.x;
    int blk=blockIdx.x, cg=blk>>6, ck=blk&63;
    int p0=cg*16, b=p0>>8, c0=p0&255;
    int l0=ck*CL_;
    {
        int lr=tid>>2, c4=tid&3;
        size_t base=((size_t)(b*L_+l0+lr))*C_ + c0 + c4*4;
        float4 x4=*(const float4*)(seqx+base);
        float4 d4=*(const float4*)(dtlc+base);
        dxL[lr][c4*4+0]=make_float2(d4.x,x4.x);
        dxL[lr][c4*4+1]=make_float2(d4.y,x4.y);
        dxL[lr][c4*4+2]=make_float2(d4.z,x4.z);
        dxL[lr][c4*4+3]=make_float2(d4.w,x4.w);
        const float* bs=BC+((size_t)(b*L_+l0+lr))*32 + c4*8;
        float4 bv0=*(const float4*)bs, bv1=*(const float4*)(bs+4);
        *(float4*)&bcL[lr][c4*8]=bv0;
        *(float4*)&bcL[lr][c4*8+4]=bv1;
    }
    __syncthreads();
    int wv=tid>>6, lane=tid&63, grp=lane>>4, n=lane&15;
    int cl=wv*4+grp, pair=p0+cl, c=c0+cl;
    float An=-__expf(A_log[c*16+n]);
    float Dc=Dsk[c];
    float carry=Sb[(pair*CK_+ck)*16+n];
    float ybuf[4], xsv[4];
    #pragma unroll
    for(int q=0;q<4;q++){
        float parts[16];
        #pragma unroll
        for(int l2=0;l2<16;l2++){
            int l=q*16+l2;
            float2 dx=dxL[l][cl];
            float bv=bcL[l][n];
            float cv=bcL[l][16+n];
            float dA=__expf(dx.x*An);
            carry=fmaf(dA,carry,dx.x*bv*dx.y);
            parts[l2]=carry*cv;
            if(l2==n) xsv[q]=dx.y;
        }
        #pragma unroll
        for(int l2=0;l2<16;l2++) sc[cl][l2][n]=parts[l2];
        __syncthreads();
        float s=0.f;
        #pragma unroll
        for(int n2=0;n2<16;n2++) s+=sc[cl][n][n2];
        ybuf[q]=fmaf(Dc,xsv[q],s);
        __syncthreads();
    }
    // stage y through LDS (reuse sc) for coalesced float4 writes
    float* yT=(float*)&sc[0][0][0];     // [64][17]
    #pragma unroll
    for(int q=0;q<4;q++){
        int l=q*16+n;
        yT[l*17+cl]=ybuf[q];
    }
    __syncthreads();
    {
        int lr=tid>>2, c4=tid&3;
        size_t base=((size_t)(b*L_+l0+lr))*C_ + c0 + c4*4;
        float4 o=make_float4(yT[lr*17+c4*4+0],yT[lr*17+c4*4+1],
                             yT[lr*17+c4*4+2],yT[lr*17+c4*4+3]);
        *(float4*)(y+base)=o;
    }
}

// ---------------- unflip + out-LN + gate by SiLU(z) -> y2b (bf16); wave-per-row ----------------
__global__ __launch_bounds__(256) void k_post(
    const float* __restrict__ y, const float* __restrict__ z,
    const float* __restrict__ og, const float* __restrict__ ob,
    unsigned short* __restrict__ y2b, int ori)
{
    int wv=threadIdx.x>>6, lane=threadIdx.x&63;
    int row=blockIdx.x*4+wv;         // b*L + l
    int b=row>>12, l=row&4095;
    int d=l&15, w=(l>>4)&15, h=l>>8;
    int hf=(ori&1)?15-h:h, wf=(ori&2)?15-w:w, df=(ori&4)?15-d:d;
    int lf=(hf*16+wf)*16+df;
    float4 v=((const float4*)(y+((size_t)b*L_+lf)*C_))[lane];
    float s=v.x+v.y+v.z+v.w;
    float ss=v.x*v.x+v.y*v.y+v.z*v.z+v.w*v.w;
    #pragma unroll
    for(int m=1;m<64;m<<=1){ s+=__shfl_xor(s,m); ss+=__shfl_xor(ss,m); }
    float mn=s*(1.f/256.f);
    float rstd=rsqrtf(ss*(1.f/256.f)-mn*mn+1e-5f);
    float4 gg=((const float4*)og)[lane];
    float4 bb=((const float4*)ob)[lane];
    float4 zv=((const float4*)(z+((size_t)b*L_+l)*C_))[lane];
    ushort4 o;
    o.x=f2b_(((v.x-mn)*rstd*gg.x+bb.x)*silu_(zv.x));
    o.y=f2b_(((v.y-mn)*rstd*gg.y+bb.y)*silu_(zv.y));
    o.z=f2b_(((v.z-mn)*rstd*gg.z+bb.z)*silu_(zv.z));
    o.w=f2b_(((v.w-mn)*rstd*gg.w+bb.w)*silu_(zv.w));
    ((ushort4*)(y2b+((size_t)b*L_+l)*C_))[lane]=o;
}

// ---------------- final LN + transpose out ----------------
__global__ __launch_bounds__(256) void k_final(
    const float* __restrict__ t, const float* __restrict__ pg,
    const float* __restrict__ pb, float* __restrict__ out)
{
    __shared__ float tile[16*257];
    __shared__ float mrs[16][2];
    int blk=blockIdx.x, b=blk>>8, d=(blk>>4)&15, h=blk&15;
    int tid=threadIdx.x;
    for(int w2=0;w2<16;w2++){
        tile[w2*257+tid]=t[((size_t)b*L_+(h*16+w2)*16+d)*C_+tid];
    }
    __syncthreads();
    int r=tid>>4, p=tid&15;
    float s=0.f, ss=0.f;
    #pragma unroll
    for(int k=0;k<16;k++){ float v=tile[r*257+k*16+p]; s+=v; ss+=v*v; }
    #pragma unroll
    for(int m=1;m<16;m<<=1){ s+=__shfl_xor(s,m); ss+=__shfl_xor(ss,m); }
    if(p==0){ float mn=s*(1.f/256.f); mrs[r][0]=mn; mrs[r][1]=rsqrtf(ss*(1.f/256.f)-mn*mn+1e-5f); }
    __syncthreads();
    int w2=tid&15;
    for(int p2=0;p2<16;p2++){
        int c=(tid>>4)+16*p2;
        float v=tile[w2*257+c];
        float vn=(v-mrs[w2][0])*mrs[w2][1]*pg[c]+pb[c];
        out[((size_t)(b*C_+c))*4096 + d*256 + h*16 + w2]=vn;
    }
}

extern "C" void kernel_launch(void* const* d_in, const int* in_sizes, int n_in,
                              void* d_out, int out_size, void* d_ws, size_t ws_size,
                              hipStream_t stream)
{
    (void)in_sizes; (void)n_in; (void)out_size; (void)ws_size;
    const float* x      =(const float*)d_in[0];
    const float* in_w   =(const float*)d_in[1];
    const float* conv_w =(const float*)d_in[2];
    const float* conv_b =(const float*)d_in[3];
    const float* xproj_w=(const float*)d_in[4];
    const float* dt_w   =(const float*)d_in[5];
    const float* dt_b   =(const float*)d_in[6];
    const float* A_log  =(const float*)d_in[7];
    const float* D_skip =(const float*)d_in[8];
    const float* on_g   =(const float*)d_in[9];
    const float* on_b   =(const float*)d_in[10];
    const float* out_w  =(const float*)d_in[11];
    const float* ln1_g  =(const float*)d_in[12];
    const float* ln1_b  =(const float*)d_in[13];
    const float* post_g =(const float*)d_in[14];
    const float* post_b =(const float*)d_in[15];
    float* out=(float*)d_out;
    float* ws=(float*)d_ws;

    const size_t NBL=(size_t)BL_*C_;     // 2,097,152 elems
    float* t    = ws;                     // residual stream [B][L][C]
    float* xs   = ws +   NBL;             // conv input; reused as dtlc after conv
    float* z    = ws + 2*NBL;
    float* seq  = ws + 3*NBL;             // conv output [l][c] fp32; scan3 writes y in-place
    float* BC   = ws + 4*NBL;             // [B*L][32] fp32 (Bm | Cm)
    float* Ap   = BC + (size_t)BL_*32;
    float* Ho   = Ap + 512*CK_*16;
    float* Sb   = Ho + 512*CK_*16;
    unsigned short* hb   = (unsigned short*)(Sb + 512*CK_*16);  // bf16 LN'd activations
    unsigned short* seqb = hb   + NBL;                          // bf16 conv output
    unsigned short* y2b  = seqb + NBL;                          // bf16 gated output
    unsigned short* wbI  = y2b  + NBL;                          // bf16 in_w  (4*512*256)
    unsigned short* wbO  = wbI + (size_t)DEPTH_*512*C_;         // bf16 out_w (4*256*256)
    unsigned short* xwb  = wbO + (size_t)DEPTH_*C_*C_;          // bf16 xproj_w (4*48*256)
    unsigned short* wdtb = xwb + (size_t)DEPTH_*48*C_;          // bf16 W_eff (4*256*256)
    float* dtlc = xs;                     // dt[l][c] fp32 — aliases xs (dead after conv)

    k_w2b<<<DEPTH_*512*C_/1024,256,0,stream>>>(in_w, wbI);
    k_w2b<<<DEPTH_*C_*C_/1024,256,0,stream>>>(out_w, wbO);
    k_w2b<<<DEPTH_*48*C_/1024,256,0,stream>>>(xproj_w, xwb);
    k_wdt<<<DEPTH_*C_,256,0,stream>>>(dt_w, xproj_w, wdtb);
    k_t_in<<<512,256,0,stream>>>(x,t);
    for(int i=0;i<DEPTH_;i++){
        int ori=i&7;
        k_ln<<<2048,256,0,stream>>>(t, ln1_g+i*256, ln1_b+i*256, hb);
        k_gemm_in<<<dim3(128,8),256,0,stream>>>(hb, wbI+(size_t)i*512*C_, xs, z);
        k_conv<<<512,256,0,stream>>>(xs, conv_w+(size_t)i*6912, conv_b+i*256, seq, seqb, ori);
        k_gemm_x<<<64,256,0,stream>>>(seqb, xwb+(size_t)i*48*C_, BC);
        k_gemm_dt<<<dim3(128,4),256,0,stream>>>(seqb, wdtb+(size_t)i*C_*C_, dt_b+i*256, dtlc);
        k_scan1<<<2048,256,0,stream>>>(seq, dtlc, BC, A_log+(size_t)i*4096, Ap, Ho);
        k_scan2<<<32,256,0,stream>>>(Ap, Ho, Sb);
        k_scan3<<<2048,256,0,stream>>>(seq, dtlc, BC, A_log+(size_t)i*4096, D_skip+i*256, Sb, seq);
        k_post<<<2048,256,0,stream>>>(seq, z, on_g+i*256, on_b+i*256, y2b, ori);
        k_gemm_out<<<dim3(128,4),256,0,stream>>>(y2b, wbO+(size_t)i*C_*C_, t);
    }
    k_final<<<512,256,0,stream>>>(t, post_g, post_b, out);
}

// Round 12
// 508.776 us; speedup vs baseline: 3.0458x; 1.0210x over previous
//
#include <hip/hip_runtime.h>
#include <math.h>

#define B_ 2
#define C_ 256
#define L_ 4096
#define BL_ 8192
#define DEPTH_ 4
#define CK_ 64   // chunks per sequence
#define CL_ 64   // chunk length

typedef __attribute__((ext_vector_type(8))) short bf16x8;
typedef __attribute__((ext_vector_type(4))) float f32x4;
#define MFMA16 __builtin_amdgcn_mfma_f32_16x16x32_bf16

__device__ __forceinline__ float silu_(float x){ return x/(1.f+__expf(-x)); }
__device__ __forceinline__ float softplus_(float x){ return fmaxf(x,0.f)+log1pf(__expf(-fabsf(x))); }
__device__ __forceinline__ unsigned short f2b_(float f){
    union{float f;unsigned u;}v; v.f=f;
    unsigned r=(v.u + 0x7fffu + ((v.u>>16)&1u))>>16;
    return (unsigned short)r;
}
__device__ __forceinline__ float b2f_(unsigned short u){
    union{unsigned u;float f;}v; v.u=((unsigned)u)<<16; return v.f;
}

// ---------------- fp32 -> bf16 weight conversion ----------------
__global__ __launch_bounds__(256) void k_w2b(const float* __restrict__ src, unsigned short* __restrict__ dst)
{
    int i=blockIdx.x*256+threadIdx.x;
    float4 v=((const float4*)src)[i];
    ushort4 o; o.x=f2b_(v.x); o.y=f2b_(v.y); o.z=f2b_(v.z); o.w=f2b_(v.w);
    ((ushort4*)dst)[i]=o;
}

// ---------------- composed dt weight: W_eff[i][c][k] = sum_j dt_w[i][c][j]*xw[i][j][k] -> bf16 ----------------
__global__ __launch_bounds__(256) void k_wdt(
    const float* __restrict__ dtw, const float* __restrict__ xw,
    unsigned short* __restrict__ wdtb)
{
    int blk=blockIdx.x;          // i*256 + c
    int i=blk>>8, c=blk&255, k=threadIdx.x;
    const float* dr=dtw+((size_t)i*C_+c)*16;
    const float* xr=xw+(size_t)i*48*C_+k;
    float acc=0.f;
    #pragma unroll
    for(int j=0;j<16;j++) acc=fmaf(dr[j], xr[(size_t)j*C_], acc);
    wdtb[((size_t)i*C_+c)*C_+k]=f2b_(acc);
}

// ---------------- transpose in: x (B,C,D,H,W) -> t [B][L][C], l=(h*16+w)*16+d ----------------
__global__ __launch_bounds__(256) void k_t_in(const float* __restrict__ x, float* __restrict__ t)
{
    __shared__ float tile[16*257];
    int blk=blockIdx.x, b=blk>>8, d=(blk>>4)&15, h=blk&15;
    int tid=threadIdx.x;
    int w2=tid&15;
    for(int p=0;p<16;p++){
        int c=(tid>>4)+16*p;
        tile[w2*257+c]=x[((size_t)(b*C_+c))*4096 + d*256 + h*16 + w2];
    }
    __syncthreads();
    for(int k=0;k<16;k++){
        t[((size_t)b*L_+(h*16+k)*16+d)*C_+tid]=tile[k*257+tid];
    }
}

// ---------------- LN1: t -> hb (bf16 [M][256]) ----------------
__global__ __launch_bounds__(256) void k_ln(
    const float* __restrict__ t, const float* __restrict__ g,
    const float* __restrict__ be, unsigned short* __restrict__ hb)
{
    int wv=threadIdx.x>>6, lane=threadIdx.x&63;
    int row=blockIdx.x*4+wv;
    float4 v=((const float4*)(t+(size_t)row*C_))[lane];
    float s=v.x+v.y+v.z+v.w;
    float ss=v.x*v.x+v.y*v.y+v.z*v.z+v.w*v.w;
    #pragma unroll
    for(int m=1;m<64;m<<=1){ s+=__shfl_xor(s,m); ss+=__shfl_xor(ss,m); }
    float mn=s*(1.f/256.f);
    float rs=rsqrtf(ss*(1.f/256.f)-mn*mn+1e-5f);
    float4 gg=((const float4*)g)[lane];
    float4 bb=((const float4*)be)[lane];
    ushort4 o;
    o.x=f2b_((v.x-mn)*rs*gg.x+bb.x);
    o.y=f2b_((v.y-mn)*rs*gg.y+bb.y);
    o.z=f2b_((v.z-mn)*rs*gg.z+bb.z);
    o.w=f2b_((v.w-mn)*rs*gg.w+bb.w);
    ((ushort4*)(hb+(size_t)row*C_))[lane]=o;
}

// ---------------- MFMA GEMM: xs|z[m][n] = hb[m][k] * Wt[n][k] ; N=512 split ----------------
__global__ __launch_bounds__(256) void k_gemm_in(
    const unsigned short* __restrict__ Ab, const unsigned short* __restrict__ Wb,
    float* __restrict__ xs, float* __restrict__ z)
{
    int wv=threadIdx.x>>6, lane=threadIdx.x&63;
    int m0=blockIdx.x*64+(wv>>1)*32;
    int n0=blockIdx.y*64+(wv&1)*32;
    int la=lane&15, kg=lane>>4;
    f32x4 acc[2][2];
    #pragma unroll
    for(int i=0;i<2;i++)
        #pragma unroll
        for(int j=0;j<2;j++) acc[i][j]=(f32x4){0.f,0.f,0.f,0.f};
    const unsigned short* a0p=Ab+(size_t)(m0+la)*C_+kg*8;
    const unsigned short* a1p=Ab+(size_t)(m0+16+la)*C_+kg*8;
    const unsigned short* b0p=Wb+(size_t)(n0+la)*C_+kg*8;
    const unsigned short* b1p=Wb+(size_t)(n0+16+la)*C_+kg*8;
    #pragma unroll
    for(int kk=0;kk<C_;kk+=32){
        bf16x8 a0=*(const bf16x8*)(a0p+kk);
        bf16x8 a1=*(const bf16x8*)(a1p+kk);
        bf16x8 b0=*(const bf16x8*)(b0p+kk);
        bf16x8 b1=*(const bf16x8*)(b1p+kk);
        acc[0][0]=MFMA16(a0,b0,acc[0][0],0,0,0);
        acc[0][1]=MFMA16(a0,b1,acc[0][1],0,0,0);
        acc[1][0]=MFMA16(a1,b0,acc[1][0],0,0,0);
        acc[1][1]=MFMA16(a1,b1,acc[1][1],0,0,0);
    }
    #pragma unroll
    for(int mi=0;mi<2;mi++)
        #pragma unroll
        for(int nj=0;nj<2;nj++)
            #pragma unroll
            for(int r=0;r<4;r++){
                int m=m0+mi*16+kg*4+r;
                int n=n0+nj*16+la;
                float val=acc[mi][nj][r];
                if(n<256) xs[(size_t)m*C_+n]=val;
                else      z [(size_t)m*C_+(n-256)]=val;
            }
}

// ---------------- MFMA GEMM + residual: t[m][n] += y2b[m][k] * Wt[n][k] ----------------
__global__ __launch_bounds__(256) void k_gemm_out(
    const unsigned short* __restrict__ Ab, const unsigned short* __restrict__ Wb,
    float* __restrict__ t)
{
    int wv=threadIdx.x>>6, lane=threadIdx.x&63;
    int m0=blockIdx.x*64+(wv>>1)*32;
    int n0=blockIdx.y*64+(wv&1)*32;
    int la=lane&15, kg=lane>>4;
    f32x4 acc[2][2];
    #pragma unroll
    for(int i=0;i<2;i++)
        #pragma unroll
        for(int j=0;j<2;j++) acc[i][j]=(f32x4){0.f,0.f,0.f,0.f};
    const unsigned short* a0p=Ab+(size_t)(m0+la)*C_+kg*8;
    const unsigned short* a1p=Ab+(size_t)(m0+16+la)*C_+kg*8;
    const unsigned short* b0p=Wb+(size_t)(n0+la)*C_+kg*8;
    const unsigned short* b1p=Wb+(size_t)(n0+16+la)*C_+kg*8;
    #pragma unroll
    for(int kk=0;kk<C_;kk+=32){
        bf16x8 a0=*(const bf16x8*)(a0p+kk);
        bf16x8 a1=*(const bf16x8*)(a1p+kk);
        bf16x8 b0=*(const bf16x8*)(b0p+kk);
        bf16x8 b1=*(const bf16x8*)(b1p+kk);
        acc[0][0]=MFMA16(a0,b0,acc[0][0],0,0,0);
        acc[0][1]=MFMA16(a0,b1,acc[0][1],0,0,0);
        acc[1][0]=MFMA16(a1,b0,acc[1][0],0,0,0);
        acc[1][1]=MFMA16(a1,b1,acc[1][1],0,0,0);
    }
    #pragma unroll
    for(int mi=0;mi<2;mi++)
        #pragma unroll
        for(int nj=0;nj<2;nj++)
            #pragma unroll
            for(int r=0;r<4;r++){
                int m=m0+mi*16+kg*4+r;
                int n=n0+nj*16+la;
                float* tp=t+(size_t)m*C_+n;
                *tp=*tp+acc[mi][nj][r];
            }
}

// ---------------- fused MFMA GEMM: BC (by==4) + dt (by<4) from seqb ----------------
__global__ __launch_bounds__(256) void k_gemm_xdt(
    const unsigned short* __restrict__ Ab, const unsigned short* __restrict__ Wxb,
    const unsigned short* __restrict__ Wdtb, const float* __restrict__ dtbias,
    float* __restrict__ BC, float* __restrict__ dt)
{
    int by=blockIdx.y;
    int wv=threadIdx.x>>6, lane=threadIdx.x&63;
    int la=lane&15, kg=lane>>4;
    f32x4 acc[2][2];
    #pragma unroll
    for(int i=0;i<2;i++)
        #pragma unroll
        for(int j=0;j<2;j++) acc[i][j]=(f32x4){0.f,0.f,0.f,0.f};
    if(by==4){
        if(blockIdx.x>=64) return;
        int m0=blockIdx.x*128+wv*32;
        const unsigned short* a0p=Ab+(size_t)(m0+la)*C_+kg*8;
        const unsigned short* a1p=Ab+(size_t)(m0+16+la)*C_+kg*8;
        const unsigned short* b0p=Wxb+(size_t)(16+la)*C_+kg*8;   // B rows
        const unsigned short* b1p=Wxb+(size_t)(32+la)*C_+kg*8;   // C rows
        #pragma unroll
        for(int kk=0;kk<C_;kk+=32){
            bf16x8 a0=*(const bf16x8*)(a0p+kk);
            bf16x8 a1=*(const bf16x8*)(a1p+kk);
            bf16x8 b0=*(const bf16x8*)(b0p+kk);
            bf16x8 b1=*(const bf16x8*)(b1p+kk);
            acc[0][0]=MFMA16(a0,b0,acc[0][0],0,0,0);
            acc[0][1]=MFMA16(a0,b1,acc[0][1],0,0,0);
            acc[1][0]=MFMA16(a1,b0,acc[1][0],0,0,0);
            acc[1][1]=MFMA16(a1,b1,acc[1][1],0,0,0);
        }
        #pragma unroll
        for(int mi=0;mi<2;mi++)
            #pragma unroll
            for(int nj=0;nj<2;nj++)
                #pragma unroll
                for(int r=0;r<4;r++){
                    int m=m0+mi*16+kg*4+r;
                    BC[(size_t)m*32 + nj*16+la]=acc[mi][nj][r];
                }
    } else {
        int m0=blockIdx.x*64+(wv>>1)*32;
        int n0=by*64+(wv&1)*32;
        const unsigned short* a0p=Ab+(size_t)(m0+la)*C_+kg*8;
        const unsigned short* a1p=Ab+(size_t)(m0+16+la)*C_+kg*8;
        const unsigned short* b0p=Wdtb+(size_t)(n0+la)*C_+kg*8;
        const unsigned short* b1p=Wdtb+(size_t)(n0+16+la)*C_+kg*8;
        #pragma unroll
        for(int kk=0;kk<C_;kk+=32){
            bf16x8 a0=*(const bf16x8*)(a0p+kk);
            bf16x8 a1=*(const bf16x8*)(a1p+kk);
            bf16x8 b0=*(const bf16x8*)(b0p+kk);
            bf16x8 b1=*(const bf16x8*)(b1p+kk);
            acc[0][0]=MFMA16(a0,b0,acc[0][0],0,0,0);
            acc[0][1]=MFMA16(a0,b1,acc[0][1],0,0,0);
            acc[1][0]=MFMA16(a1,b0,acc[1][0],0,0,0);
            acc[1][1]=MFMA16(a1,b1,acc[1][1],0,0,0);
        }
        float bias0=dtbias[n0+la], bias1=dtbias[n0+16+la];
        #pragma unroll
        for(int mi=0;mi<2;mi++)
            #pragma unroll
            for(int nj=0;nj<2;nj++)
                #pragma unroll
                for(int r=0;r<4;r++){
                    int m=m0+mi*16+kg*4+r;
                    int n=n0+nj*16+la;
                    float val=acc[mi][nj][r]+((nj==0)?bias0:bias1);
                    dt[(size_t)m*C_+n]=softplus_(val);
                }
    }
}

// ---------------- depthwise conv3x3x3, register-blocked along d; bf16 output only ----------------
__global__ __launch_bounds__(256) void k_conv(
    const float* __restrict__ xs, const float* __restrict__ cw,
    const float* __restrict__ cb, unsigned short* __restrict__ seqb, int ori)
{
    __shared__ float wl[256*27];
    int tid=threadIdx.x;
    for(int j=tid;j<256*27;j+=256) wl[j]=cw[j];
    int blk=blockIdx.x;          // b*256 + h*16 + w
    int b=blk>>8, h=(blk>>4)&15, w=blk&15;
    __syncthreads();
    const float* wp=wl+tid*27;
    float bias=cb[tid];
    float acc[16];
    #pragma unroll
    for(int d=0;d<16;d++) acc[d]=bias;
    #pragma unroll
    for(int kh=0;kh<3;kh++){
        int hh=h+kh-1; if((unsigned)hh>=16u) continue;
        #pragma unroll
        for(int kw=0;kw<3;kw++){
            int ww=w+kw-1; if((unsigned)ww>=16u) continue;
            const float* bp=xs+((size_t)(b*L_)+(hh*16+ww)*16)*C_+tid;
            float w0=wp[(kh*3+kw)*3+0];
            float w1=wp[(kh*3+kw)*3+1];
            float w2=wp[(kh*3+kw)*3+2];
            #pragma unroll
            for(int dd=0;dd<16;dd++){
                float v=bp[(size_t)dd*C_];
                if(dd<15) acc[dd+1]=fmaf(w0,v,acc[dd+1]);
                acc[dd]=fmaf(w1,v,acc[dd]);
                if(dd>0)  acc[dd-1]=fmaf(w2,v,acc[dd-1]);
            }
        }
    }
    int hf=(ori&1)?15-h:h;
    int wf=(ori&2)?15-w:w;
    size_t obase=((size_t)b*L_+(hf*16+wf)*16)*C_+tid;
    #pragma unroll
    for(int d=0;d<16;d++){
        float a=silu_(acc[d]);
        int df=(ori&4)?15-d:d;
        seqb[obase+(size_t)df*C_]=f2b_(a);
    }
}

// ---------------- chunked selective scan (corner-turn tiles; x from bf16) ----------------
__global__ __launch_bounds__(256) void k_scan1(
    const unsigned short* __restrict__ seqb, const float* __restrict__ dtlc,
    const float* __restrict__ BC, const float* __restrict__ A_log,
    float* __restrict__ Ap, float* __restrict__ Ho)
{
    __shared__ float2 dxL[64][17];
    __shared__ float  bcL[64][16];
    int tid=threadIdx.x;
    int blk=blockIdx.x, cg=blk>>6, ck=blk&63;
    int p0=cg*16, b=p0>>8, c0=p0&255;
    int l0=ck*CL_;
    {
        int lr=tid>>2, c4=tid&3;
        size_t base=((size_t)(b*L_+l0+lr))*C_ + c0 + c4*4;
        ushort4 xu=*(const ushort4*)(seqb+base);
        float4 d4=*(const float4*)(dtlc+base);
        dxL[lr][c4*4+0]=make_float2(d4.x,b2f_(xu.x));
        dxL[lr][c4*4+1]=make_float2(d4.y,b2f_(xu.y));
        dxL[lr][c4*4+2]=make_float2(d4.z,b2f_(xu.z));
        dxL[lr][c4*4+3]=make_float2(d4.w,b2f_(xu.w));
        if(c4==0){
            const float* bs=BC+((size_t)(b*L_+l0+lr))*32;
            float4 bv0=*(const float4*)bs, bv1=*(const float4*)(bs+4);
            float4 bv2=*(const float4*)(bs+8), bv3=*(const float4*)(bs+12);
            *(float4*)&bcL[lr][0]=bv0;  *(float4*)&bcL[lr][4]=bv1;
            *(float4*)&bcL[lr][8]=bv2;  *(float4*)&bcL[lr][12]=bv3;
        }
    }
    __syncthreads();
    int wv=tid>>6, lane=tid&63, grp=lane>>4, n=lane&15;
    int cl=wv*4+grp, pair=p0+cl, c=c0+cl;
    float An=-__expf(A_log[c*16+n]);
    float carry=0.f, sdt=0.f;
    #pragma unroll 8
    for(int l=0;l<CL_;l++){
        float2 dx=dxL[l][cl];
        float bv=bcL[l][n];
        float dA=__expf(dx.x*An);
        carry=fmaf(dA,carry,dx.x*bv*dx.y);
        sdt+=dx.x;
    }
    int idx=(pair*CK_+ck)*16+n;
    Ap[idx]=__expf(An*sdt); Ho[idx]=carry;
}

__global__ __launch_bounds__(256) void k_scan2(
    const float* __restrict__ Ap, const float* __restrict__ Ho, float* __restrict__ Sb)
{
    int gid=blockIdx.x*256+threadIdx.x;
    int pair=gid>>4, n=gid&15;
    float S=0.f;
    #pragma unroll
    for(int ck=0;ck<CK_;ck++){
        int idx=(pair*CK_+ck)*16+n;
        Sb[idx]=S;
        S=fmaf(Ap[idx],S,Ho[idx]);
    }
}

// scan3: replay with carry-in; shuffle-free LDS transpose reduction
__global__ __launch_bounds__(256) void k_scan3(
    const unsigned short* __restrict__ seqb, const float* __restrict__ dtlc,
    const float* __restrict__ BC, const float* __restrict__ A_log,
    const float* __restrict__ Dsk, const float* __restrict__ Sb,
    float* __restrict__ y)
{
    __shared__ float2 dxL[64][17];
    __shared__ float  bcL[64][32];
    __shared__ float  sc[16][16][17];   // [cl][l2][n+pad]; reused as y tile
    int tid=threadIdx.x;
    int blk=blockIdx.x, cg=blk>>6, ck=blk&63;
    int p0=cg*16, b=p0>>8, c0=p0&255;
    int l0=ck*CL_;
    {
        int lr=tid>>2, c4=tid&3;
        size_t base=((size_t)(b*L_+l0+lr))*C_ + c0 + c4*4;
        ushort4 xu=*(const ushort4*)(seqb+base);
        float4 d4=*(const float4*)(dtlc+base);
        dxL[lr][c4*4+0]=make_float2(d4.x,b2f_(xu.x));
        dxL[lr][c4*4+1]=make_float2(d4.y,b2f_(xu.y));
        dxL[lr][c4*4+2]=make_float2(d4.z,b2f_(xu.z));
        dxL[lr][c4*4+3]=make_float2(d4.w,b2f_(xu.w));
        const float* bs=BC+((size_t)(b*L_+l0+lr))*32 + c4*8;
        float4 bv0=*(const float4*)bs, bv1=*(const float4*)(bs+4);
        *(float4*)&bcL[lr][c4*8]=bv0;
        *(float4*)&bcL[lr][c4*8+4]=bv1;
    }
    __syncthreads();
    int wv=tid>>6, lane=tid&63, grp=lane>>4, n=lane&15;
    int cl=wv*4+grp, pair=p0+cl, c=c0+cl;
    float An=-__expf(A_log[c*16+n]);
    float Dc=Dsk[c];
    float carry=Sb[(pair*CK_+ck)*16+n];
    float ybuf[4], xsv[4];
    #pragma unroll
    for(int q=0;q<4;q++){
        float parts[16];
        #pragma unroll
        for(int l2=0;l2<16;l2++){
            int l=q*16+l2;
            float2 dx=dxL[l][cl];
            float bv=bcL[l][n];
            float cv=bcL[l][16+n];
            float dA=__expf(dx.x*An);
            carry=fmaf(dA,carry,dx.x*bv*dx.y);
            parts[l2]=carry*cv;
            if(l2==n) xsv[q]=dx.y;
        }
        #pragma unroll
        for(int l2=0;l2<16;l2++) sc[cl][l2][n]=parts[l2];
        __syncthreads();
        float s=0.f;
        #pragma unroll
        for(int n2=0;n2<16;n2++) s+=sc[cl][n][n2];
        ybuf[q]=fmaf(Dc,xsv[q],s);
        __syncthreads();
    }
    float* yT=(float*)&sc[0][0][0];     // [64][17]
    #pragma unroll
    for(int q=0;q<4;q++){
        int l=q*16+n;
        yT[l*17+cl]=ybuf[q];
    }
    __syncthreads();
    {
        int lr=tid>>2, c4=tid&3;
        size_t base=((size_t)(b*L_+l0+lr))*C_ + c0 + c4*4;
        float4 o=make_float4(yT[lr*17+c4*4+0],yT[lr*17+c4*4+1],
                             yT[lr*17+c4*4+2],yT[lr*17+c4*4+3]);
        *(float4*)(y+base)=o;
    }
}

// ---------------- unflip + out-LN + gate by SiLU(z) -> y2b (bf16); wave-per-row ----------------
__global__ __launch_bounds__(256) void k_post(
    const float* __restrict__ y, const float* __restrict__ z,
    const float* __restrict__ og, const float* __restrict__ ob,
    unsigned short* __restrict__ y2b, int ori)
{
    int wv=threadIdx.x>>6, lane=threadIdx.x&63;
    int row=blockIdx.x*4+wv;         // b*L + l
    int b=row>>12, l=row&4095;
    int d=l&15, w=(l>>4)&15, h=l>>8;
    int hf=(ori&1)?15-h:h, wf=(ori&2)?15-w:w, df=(ori&4)?15-d:d;
    int lf=(hf*16+wf)*16+df;
    float4 v=((const float4*)(y+((size_t)b*L_+lf)*C_))[lane];
    float s=v.x+v.y+v.z+v.w;
    float ss=v.x*v.x+v.y*v.y+v.z*v.z+v.w*v.w;
    #pragma unroll
    for(int m=1;m<64;m<<=1){ s+=__shfl_xor(s,m); ss+=__shfl_xor(ss,m); }
    float mn=s*(1.f/256.f);
    float rstd=rsqrtf(ss*(1.f/256.f)-mn*mn+1e-5f);
    float4 gg=((const float4*)og)[lane];
    float4 bb=((const float4*)ob)[lane];
    float4 zv=((const float4*)(z+((size_t)b*L_+l)*C_))[lane];
    ushort4 o;
    o.x=f2b_(((v.x-mn)*rstd*gg.x+bb.x)*silu_(zv.x));
    o.y=f2b_(((v.y-mn)*rstd*gg.y+bb.y)*silu_(zv.y));
    o.z=f2b_(((v.z-mn)*rstd*gg.z+bb.z)*silu_(zv.z));
    o.w=f2b_(((v.w-mn)*rstd*gg.w+bb.w)*silu_(zv.w));
    ((ushort4*)(y2b+((size_t)b*L_+l)*C_))[lane]=o;
}

// ---------------- final LN + transpose out ----------------
__global__ __launch_bounds__(256) void k_final(
    const float* __restrict__ t, const float* __restrict__ pg,
    const float* __restrict__ pb, float* __restrict__ out)
{
    __shared__ float tile[16*257];
    __shared__ float mrs[16][2];
    int blk=blockIdx.x, b=blk>>8, d=(blk>>4)&15, h=blk&15;
    int tid=threadIdx.x;
    for(int w2=0;w2<16;w2++){
        tile[w2*257+tid]=t[((size_t)b*L_+(h*16+w2)*16+d)*C_+tid];
    }
    __syncthreads();
    int r=tid>>4, p=tid&15;
    float s=0.f, ss=0.f;
    #pragma unroll
    for(int k=0;k<16;k++){ float v=tile[r*257+k*16+p]; s+=v; ss+=v*v; }
    #pragma unroll
    for(int m=1;m<16;m<<=1){ s+=__shfl_xor(s,m); ss+=__shfl_xor(ss,m); }
    if(p==0){ float mn=s*(1.f/256.f); mrs[r][0]=mn; mrs[r][1]=rsqrtf(ss*(1.f/256.f)-mn*mn+1e-5f); }
    __syncthreads();
    int w2=tid&15;
    for(int p2=0;p2<16;p2++){
        int c=(tid>>4)+16*p2;
        float v=tile[w2*257+c];
        float vn=(v-mrs[w2][0])*mrs[w2][1]*pg[c]+pb[c];
        out[((size_t)(b*C_+c))*4096 + d*256 + h*16 + w2]=vn;
    }
}

extern "C" void kernel_launch(void* const* d_in, const int* in_sizes, int n_in,
                              void* d_out, int out_size, void* d_ws, size_t ws_size,
                              hipStream_t stream)
{
    (void)in_sizes; (void)n_in; (void)out_size; (void)ws_size;
    const float* x      =(const float*)d_in[0];
    const float* in_w   =(const float*)d_in[1];
    const float* conv_w =(const float*)d_in[2];
    const float* conv_b =(const float*)d_in[3];
    const float* xproj_w=(const float*)d_in[4];
    const float* dt_w   =(const float*)d_in[5];
    const float* dt_b   =(const float*)d_in[6];
    const float* A_log  =(const float*)d_in[7];
    const float* D_skip =(const float*)d_in[8];
    const float* on_g   =(const float*)d_in[9];
    const float* on_b   =(const float*)d_in[10];
    const float* out_w  =(const float*)d_in[11];
    const float* ln1_g  =(const float*)d_in[12];
    const float* ln1_b  =(const float*)d_in[13];
    const float* post_g =(const float*)d_in[14];
    const float* post_b =(const float*)d_in[15];
    float* out=(float*)d_out;
    float* ws=(float*)d_ws;

    const size_t NBL=(size_t)BL_*C_;     // 2,097,152 elems
    float* t    = ws;                     // residual stream [B][L][C]
    float* xs   = ws +   NBL;             // conv input; reused as dtlc after conv
    float* z    = ws + 2*NBL;
    float* seq  = ws + 3*NBL;             // scan3 writes y here (fp32)
    float* BC   = ws + 4*NBL;             // [B*L][32] fp32 (Bm | Cm)
    float* Ap   = BC + (size_t)BL_*32;
    float* Ho   = Ap + 512*CK_*16;
    float* Sb   = Ho + 512*CK_*16;
    unsigned short* hb   = (unsigned short*)(Sb + 512*CK_*16);  // bf16 LN'd activations
    unsigned short* seqb = hb   + NBL;                          // bf16 conv output
    unsigned short* y2b  = seqb + NBL;                          // bf16 gated output
    unsigned short* wbI  = y2b  + NBL;                          // bf16 in_w  (4*512*256)
    unsigned short* wbO  = wbI + (size_t)DEPTH_*512*C_;         // bf16 out_w (4*256*256)
    unsigned short* xwb  = wbO + (size_t)DEPTH_*C_*C_;          // bf16 xproj_w (4*48*256)
    unsigned short* wdtb = xwb + (size_t)DEPTH_*48*C_;          // bf16 W_eff (4*256*256)
    float* dtlc = xs;                     // dt[l][c] fp32 — aliases xs (dead after conv)

    k_w2b<<<DEPTH_*512*C_/1024,256,0,stream>>>(in_w, wbI);
    k_w2b<<<DEPTH_*C_*C_/1024,256,0,stream>>>(out_w, wbO);
    k_w2b<<<DEPTH_*48*C_/1024,256,0,stream>>>(xproj_w, xwb);
    k_wdt<<<DEPTH_*C_,256,0,stream>>>(dt_w, xproj_w, wdtb);
    k_t_in<<<512,256,0,stream>>>(x,t);
    for(int i=0;i<DEPTH_;i++){
        int ori=i&7;
        k_ln<<<2048,256,0,stream>>>(t, ln1_g+i*256, ln1_b+i*256, hb);
        k_gemm_in<<<dim3(128,8),256,0,stream>>>(hb, wbI+(size_t)i*512*C_, xs, z);
        k_conv<<<512,256,0,stream>>>(xs, conv_w+(size_t)i*6912, conv_b+i*256, seqb, ori);
        k_gemm_xdt<<<dim3(128,5),256,0,stream>>>(seqb, xwb+(size_t)i*48*C_, wdtb+(size_t)i*C_*C_, dt_b+i*256, BC, dtlc);
        k_scan1<<<2048,256,0,stream>>>(seqb, dtlc, BC, A_log+(size_t)i*4096, Ap, Ho);
        k_scan2<<<32,256,0,stream>>>(Ap, Ho, Sb);
        k_scan3<<<2048,256,0,stream>>>(seqb, dtlc, BC, A_log+(size_t)i*4096, D_skip+i*256, Sb, seq);
        k_post<<<2048,256,0,stream>>>(seq, z, on_g+i*256, on_b+i*256, y2b, ori);
        k_gemm_out<<<dim3(128,4),256,0,stream>>>(y2b, wbO+(size_t)i*C_*C_, t);
    }
    k_final<<<512,256,0,stream>>>(t, post_g, post_b, out);
}

// Round 13
// 481.151 us; speedup vs baseline: 3.2206x; 1.0574x over previous
//
#include <hip/hip_runtime.h>
#include <math.h>

#define B_ 2
#define C_ 256
#define L_ 4096
#define BL_ 8192
#define DEPTH_ 4
#define CK_ 64   // chunks per sequence
#define CL_ 64   // chunk length

typedef __attribute__((ext_vector_type(8))) short bf16x8;
typedef __attribute__((ext_vector_type(4))) float f32x4;
#define MFMA16 __builtin_amdgcn_mfma_f32_16x16x32_bf16

__device__ __forceinline__ float silu_(float x){ return x/(1.f+__expf(-x)); }
__device__ __forceinline__ float softplus_(float x){ return fmaxf(x,0.f)+log1pf(__expf(-fabsf(x))); }
__device__ __forceinline__ unsigned short f2b_(float f){
    union{float f;unsigned u;}v; v.f=f;
    unsigned r=(v.u + 0x7fffu + ((v.u>>16)&1u))>>16;
    return (unsigned short)r;
}
__device__ __forceinline__ float b2f_(unsigned short u){
    union{unsigned u;float f;}v; v.u=((unsigned)u)<<16; return v.f;
}

// ---------------- merged prologue: all weight conversions ----------------
__global__ __launch_bounds__(256) void k_prep(
    const float* __restrict__ in_w, const float* __restrict__ out_w,
    const float* __restrict__ xproj_w, const float* __restrict__ dtw,
    unsigned short* __restrict__ wbI, unsigned short* __restrict__ wbO,
    unsigned short* __restrict__ xwb, unsigned short* __restrict__ wdtb)
{
    int bid=blockIdx.x, tid=threadIdx.x;
    if(bid<512){
        int i=bid*256+tid;
        float4 v=((const float4*)in_w)[i];
        ushort4 o; o.x=f2b_(v.x); o.y=f2b_(v.y); o.z=f2b_(v.z); o.w=f2b_(v.w);
        ((ushort4*)wbI)[i]=o;
    } else if(bid<768){
        int i=(bid-512)*256+tid;
        float4 v=((const float4*)out_w)[i];
        ushort4 o; o.x=f2b_(v.x); o.y=f2b_(v.y); o.z=f2b_(v.z); o.w=f2b_(v.w);
        ((ushort4*)wbO)[i]=o;
    } else if(bid<816){
        int i=(bid-768)*256+tid;
        float4 v=((const float4*)xproj_w)[i];
        ushort4 o; o.x=f2b_(v.x); o.y=f2b_(v.y); o.z=f2b_(v.z); o.w=f2b_(v.w);
        ((ushort4*)xwb)[i]=o;
    } else {
        int blk=bid-816;             // i*256 + c
        int i=blk>>8, c=blk&255, k=tid;
        const float* dr=dtw+((size_t)i*C_+c)*16;
        const float* xr=xproj_w+(size_t)i*48*C_+k;
        float acc=0.f;
        #pragma unroll
        for(int j=0;j<16;j++) acc=fmaf(dr[j], xr[(size_t)j*C_], acc);
        wdtb[((size_t)i*C_+c)*C_+k]=f2b_(acc);
    }
}

// ---------------- transpose in: x (B,C,D,H,W) -> t [B][L][C], l=(h*16+w)*16+d ----------------
__global__ __launch_bounds__(256) void k_t_in(const float* __restrict__ x, float* __restrict__ t)
{
    __shared__ float tile[16*257];
    int blk=blockIdx.x, b=blk>>8, d=(blk>>4)&15, h=blk&15;
    int tid=threadIdx.x;
    int w2=tid&15;
    for(int p=0;p<16;p++){
        int c=(tid>>4)+16*p;
        tile[w2*257+c]=x[((size_t)(b*C_+c))*4096 + d*256 + h*16 + w2];
    }
    __syncthreads();
    for(int k=0;k<16;k++){
        t[((size_t)b*L_+(h*16+k)*16+d)*C_+tid]=tile[k*257+tid];
    }
}

// ---------------- fused LN1 + in-proj MFMA GEMM ----------------
// block: 64 A-rows (LN'd into LDS bf16) x 64 n-cols; grid (128,8)
__global__ __launch_bounds__(256) void k_ln_gemm_in(
    const float* __restrict__ t, const float* __restrict__ g,
    const float* __restrict__ be, const unsigned short* __restrict__ Wb,
    float* __restrict__ xs, float* __restrict__ z)
{
    __shared__ unsigned short A[64][264];   // +8 pad: 528B stride -> 2-way bank alias (free)
    int tid=threadIdx.x, wv=tid>>6, lane=tid&63;
    int m0=blockIdx.x*64, n0=blockIdx.y*64;
    float4 gg=((const float4*)g)[lane];
    float4 bb=((const float4*)be)[lane];
    #pragma unroll 4
    for(int i=0;i<16;i++){
        int row=wv*16+i;
        float4 v=((const float4*)(t+(size_t)(m0+row)*C_))[lane];
        float s=v.x+v.y+v.z+v.w;
        float ss=v.x*v.x+v.y*v.y+v.z*v.z+v.w*v.w;
        #pragma unroll
        for(int m=1;m<64;m<<=1){ s+=__shfl_xor(s,m); ss+=__shfl_xor(ss,m); }
        float mn=s*(1.f/256.f);
        float rs=rsqrtf(ss*(1.f/256.f)-mn*mn+1e-5f);
        ushort4 o;
        o.x=f2b_((v.x-mn)*rs*gg.x+bb.x);
        o.y=f2b_((v.y-mn)*rs*gg.y+bb.y);
        o.z=f2b_((v.z-mn)*rs*gg.z+bb.z);
        o.w=f2b_((v.w-mn)*rs*gg.w+bb.w);
        *(ushort4*)&A[row][lane*4]=o;
    }
    __syncthreads();
    int la=lane&15, kg=lane>>4;
    int mh=(wv>>1)*32, nh=n0+(wv&1)*32;
    f32x4 acc[2][2];
    #pragma unroll
    for(int i=0;i<2;i++)
        #pragma unroll
        for(int j=0;j<2;j++) acc[i][j]=(f32x4){0.f,0.f,0.f,0.f};
    const unsigned short* b0p=Wb+(size_t)(nh+la)*C_+kg*8;
    const unsigned short* b1p=Wb+(size_t)(nh+16+la)*C_+kg*8;
    #pragma unroll
    for(int kk=0;kk<C_;kk+=32){
        bf16x8 a0=*(const bf16x8*)&A[mh+la][kg*8+kk];
        bf16x8 a1=*(const bf16x8*)&A[mh+16+la][kg*8+kk];
        bf16x8 b0=*(const bf16x8*)(b0p+kk);
        bf16x8 b1=*(const bf16x8*)(b1p+kk);
        acc[0][0]=MFMA16(a0,b0,acc[0][0],0,0,0);
        acc[0][1]=MFMA16(a0,b1,acc[0][1],0,0,0);
        acc[1][0]=MFMA16(a1,b0,acc[1][0],0,0,0);
        acc[1][1]=MFMA16(a1,b1,acc[1][1],0,0,0);
    }
    #pragma unroll
    for(int mi=0;mi<2;mi++)
        #pragma unroll
        for(int nj=0;nj<2;nj++)
            #pragma unroll
            for(int r=0;r<4;r++){
                int m=m0+mh+mi*16+kg*4+r;
                int n=nh+nj*16+la;
                float val=acc[mi][nj][r];
                if(n<256) xs[(size_t)m*C_+n]=val;
                else      z [(size_t)m*C_+(n-256)]=val;
            }
}

// ---------------- fused unflip+LN+gate + out-proj MFMA GEMM + residual ----------------
// block: 64 rows (post'd into LDS bf16) x 64 n-cols; grid (128,4)
__global__ __launch_bounds__(256) void k_post_gemm_out(
    const float* __restrict__ y, const float* __restrict__ z,
    const float* __restrict__ og, const float* __restrict__ ob,
    const unsigned short* __restrict__ Wb, float* __restrict__ t, int ori)
{
    __shared__ unsigned short A[64][264];
    int tid=threadIdx.x, wv=tid>>6, lane=tid&63;
    int m0=blockIdx.x*64, n0=blockIdx.y*64;
    float4 gg=((const float4*)og)[lane];
    float4 bb=((const float4*)ob)[lane];
    #pragma unroll 4
    for(int i=0;i<16;i++){
        int row=wv*16+i;
        int rm=m0+row;
        int b=rm>>12, l=rm&4095;
        int d=l&15, w=(l>>4)&15, h=l>>8;
        int hf=(ori&1)?15-h:h, wf=(ori&2)?15-w:w, df=(ori&4)?15-d:d;
        int lf=(hf*16+wf)*16+df;
        float4 v=((const float4*)(y+((size_t)b*L_+lf)*C_))[lane];
        float s=v.x+v.y+v.z+v.w;
        float ss=v.x*v.x+v.y*v.y+v.z*v.z+v.w*v.w;
        #pragma unroll
        for(int m=1;m<64;m<<=1){ s+=__shfl_xor(s,m); ss+=__shfl_xor(ss,m); }
        float mn=s*(1.f/256.f);
        float rstd=rsqrtf(ss*(1.f/256.f)-mn*mn+1e-5f);
        float4 zv=((const float4*)(z+((size_t)b*L_+l)*C_))[lane];
        ushort4 o;
        o.x=f2b_(((v.x-mn)*rstd*gg.x+bb.x)*silu_(zv.x));
        o.y=f2b_(((v.y-mn)*rstd*gg.y+bb.y)*silu_(zv.y));
        o.z=f2b_(((v.z-mn)*rstd*gg.z+bb.z)*silu_(zv.z));
        o.w=f2b_(((v.w-mn)*rstd*gg.w+bb.w)*silu_(zv.w));
        *(ushort4*)&A[row][lane*4]=o;
    }
    __syncthreads();
    int la=lane&15, kg=lane>>4;
    int mh=(wv>>1)*32, nh=n0+(wv&1)*32;
    f32x4 acc[2][2];
    #pragma unroll
    for(int i=0;i<2;i++)
        #pragma unroll
        for(int j=0;j<2;j++) acc[i][j]=(f32x4){0.f,0.f,0.f,0.f};
    const unsigned short* b0p=Wb+(size_t)(nh+la)*C_+kg*8;
    const unsigned short* b1p=Wb+(size_t)(nh+16+la)*C_+kg*8;
    #pragma unroll
    for(int kk=0;kk<C_;kk+=32){
        bf16x8 a0=*(const bf16x8*)&A[mh+la][kg*8+kk];
        bf16x8 a1=*(const bf16x8*)&A[mh+16+la][kg*8+kk];
        bf16x8 b0=*(const bf16x8*)(b0p+kk);
        bf16x8 b1=*(const bf16x8*)(b1p+kk);
        acc[0][0]=MFMA16(a0,b0,acc[0][0],0,0,0);
        acc[0][1]=MFMA16(a0,b1,acc[0][1],0,0,0);
        acc[1][0]=MFMA16(a1,b0,acc[1][0],0,0,0);
        acc[1][1]=MFMA16(a1,b1,acc[1][1],0,0,0);
    }
    #pragma unroll
    for(int mi=0;mi<2;mi++)
        #pragma unroll
        for(int nj=0;nj<2;nj++)
            #pragma unroll
            for(int r=0;r<4;r++){
                int m=m0+mh+mi*16+kg*4+r;
                int n=nh+nj*16+la;
                float* tp=t+(size_t)m*C_+n;
                *tp=*tp+acc[mi][nj][r];
            }
}

// ---------------- fused MFMA GEMM: BC (by==4) + dt (by<4) from seqb ----------------
__global__ __launch_bounds__(256) void k_gemm_xdt(
    const unsigned short* __restrict__ Ab, const unsigned short* __restrict__ Wxb,
    const unsigned short* __restrict__ Wdtb, const float* __restrict__ dtbias,
    float* __restrict__ BC, float* __restrict__ dt)
{
    int by=blockIdx.y;
    int wv=threadIdx.x>>6, lane=threadIdx.x&63;
    int la=lane&15, kg=lane>>4;
    f32x4 acc[2][2];
    #pragma unroll
    for(int i=0;i<2;i++)
        #pragma unroll
        for(int j=0;j<2;j++) acc[i][j]=(f32x4){0.f,0.f,0.f,0.f};
    if(by==4){
        if(blockIdx.x>=64) return;
        int m0=blockIdx.x*128+wv*32;
        const unsigned short* a0p=Ab+(size_t)(m0+la)*C_+kg*8;
        const unsigned short* a1p=Ab+(size_t)(m0+16+la)*C_+kg*8;
        const unsigned short* b0p=Wxb+(size_t)(16+la)*C_+kg*8;   // B rows
        const unsigned short* b1p=Wxb+(size_t)(32+la)*C_+kg*8;   // C rows
        #pragma unroll
        for(int kk=0;kk<C_;kk+=32){
            bf16x8 a0=*(const bf16x8*)(a0p+kk);
            bf16x8 a1=*(const bf16x8*)(a1p+kk);
            bf16x8 b0=*(const bf16x8*)(b0p+kk);
            bf16x8 b1=*(const bf16x8*)(b1p+kk);
            acc[0][0]=MFMA16(a0,b0,acc[0][0],0,0,0);
            acc[0][1]=MFMA16(a0,b1,acc[0][1],0,0,0);
            acc[1][0]=MFMA16(a1,b0,acc[1][0],0,0,0);
            acc[1][1]=MFMA16(a1,b1,acc[1][1],0,0,0);
        }
        #pragma unroll
        for(int mi=0;mi<2;mi++)
            #pragma unroll
            for(int nj=0;nj<2;nj++)
                #pragma unroll
                for(int r=0;r<4;r++){
                    int m=m0+mi*16+kg*4+r;
                    BC[(size_t)m*32 + nj*16+la]=acc[mi][nj][r];
                }
    } else {
        int m0=blockIdx.x*64+(wv>>1)*32;
        int n0=by*64+(wv&1)*32;
        const unsigned short* a0p=Ab+(size_t)(m0+la)*C_+kg*8;
        const unsigned short* a1p=Ab+(size_t)(m0+16+la)*C_+kg*8;
        const unsigned short* b0p=Wdtb+(size_t)(n0+la)*C_+kg*8;
        const unsigned short* b1p=Wdtb+(size_t)(n0+16+la)*C_+kg*8;
        #pragma unroll
        for(int kk=0;kk<C_;kk+=32){
            bf16x8 a0=*(const bf16x8*)(a0p+kk);
            bf16x8 a1=*(const bf16x8*)(a1p+kk);
            bf16x8 b0=*(const bf16x8*)(b0p+kk);
            bf16x8 b1=*(const bf16x8*)(b1p+kk);
            acc[0][0]=MFMA16(a0,b0,acc[0][0],0,0,0);
            acc[0][1]=MFMA16(a0,b1,acc[0][1],0,0,0);
            acc[1][0]=MFMA16(a1,b0,acc[1][0],0,0,0);
            acc[1][1]=MFMA16(a1,b1,acc[1][1],0,0,0);
        }
        float bias0=dtbias[n0+la], bias1=dtbias[n0+16+la];
        #pragma unroll
        for(int mi=0;mi<2;mi++)
            #pragma unroll
            for(int nj=0;nj<2;nj++)
                #pragma unroll
                for(int r=0;r<4;r++){
                    int m=m0+mi*16+kg*4+r;
                    int n=n0+nj*16+la;
                    float val=acc[mi][nj][r]+((nj==0)?bias0:bias1);
                    dt[(size_t)m*C_+n]=softplus_(val);
                }
    }
}

// ---------------- depthwise conv3x3x3, register-blocked along d; bf16 output only ----------------
__global__ __launch_bounds__(256) void k_conv(
    const float* __restrict__ xs, const float* __restrict__ cw,
    const float* __restrict__ cb, unsigned short* __restrict__ seqb, int ori)
{
    __shared__ float wl[256*27];
    int tid=threadIdx.x;
    for(int j=tid;j<256*27;j+=256) wl[j]=cw[j];
    int blk=blockIdx.x;          // b*256 + h*16 + w
    int b=blk>>8, h=(blk>>4)&15, w=blk&15;
    __syncthreads();
    const float* wp=wl+tid*27;
    float bias=cb[tid];
    float acc[16];
    #pragma unroll
    for(int d=0;d<16;d++) acc[d]=bias;
    #pragma unroll
    for(int kh=0;kh<3;kh++){
        int hh=h+kh-1; if((unsigned)hh>=16u) continue;
        #pragma unroll
        for(int kw=0;kw<3;kw++){
            int ww=w+kw-1; if((unsigned)ww>=16u) continue;
            const float* bp=xs+((size_t)(b*L_)+(hh*16+ww)*16)*C_+tid;
            float w0=wp[(kh*3+kw)*3+0];
            float w1=wp[(kh*3+kw)*3+1];
            float w2=wp[(kh*3+kw)*3+2];
            #pragma unroll
            for(int dd=0;dd<16;dd++){
                float v=bp[(size_t)dd*C_];
                if(dd<15) acc[dd+1]=fmaf(w0,v,acc[dd+1]);
                acc[dd]=fmaf(w1,v,acc[dd]);
                if(dd>0)  acc[dd-1]=fmaf(w2,v,acc[dd-1]);
            }
        }
    }
    int hf=(ori&1)?15-h:h;
    int wf=(ori&2)?15-w:w;
    size_t obase=((size_t)b*L_+(hf*16+wf)*16)*C_+tid;
    #pragma unroll
    for(int d=0;d<16;d++){
        float a=silu_(acc[d]);
        int df=(ori&4)?15-d:d;
        seqb[obase+(size_t)df*C_]=f2b_(a);
    }
}

// ---------------- chunked selective scan (corner-turn tiles; x from bf16) ----------------
__global__ __launch_bounds__(256) void k_scan1(
    const unsigned short* __restrict__ seqb, const float* __restrict__ dtlc,
    const float* __restrict__ BC, const float* __restrict__ A_log,
    float* __restrict__ Ap, float* __restrict__ Ho)
{
    __shared__ float2 dxL[64][17];
    __shared__ float  bcL[64][16];
    int tid=threadIdx.x;
    int blk=blockIdx.x, cg=blk>>6, ck=blk&63;
    int p0=cg*16, b=p0>>8, c0=p0&255;
    int l0=ck*CL_;
    {
        int lr=tid>>2, c4=tid&3;
        size_t base=((size_t)(b*L_+l0+lr))*C_ + c0 + c4*4;
        ushort4 xu=*(const ushort4*)(seqb+base);
        float4 d4=*(const float4*)(dtlc+base);
        dxL[lr][c4*4+0]=make_float2(d4.x,b2f_(xu.x));
        dxL[lr][c4*4+1]=make_float2(d4.y,b2f_(xu.y));
        dxL[lr][c4*4+2]=make_float2(d4.z,b2f_(xu.z));
        dxL[lr][c4*4+3]=make_float2(d4.w,b2f_(xu.w));
        if(c4==0){
            const float* bs=BC+((size_t)(b*L_+l0+lr))*32;
            float4 bv0=*(const float4*)bs, bv1=*(const float4*)(bs+4);
            float4 bv2=*(const float4*)(bs+8), bv3=*(const float4*)(bs+12);
            *(float4*)&bcL[lr][0]=bv0;  *(float4*)&bcL[lr][4]=bv1;
            *(float4*)&bcL[lr][8]=bv2;  *(float4*)&bcL[lr][12]=bv3;
        }
    }
    __syncthreads();
    int wv=tid>>6, lane=tid&63, grp=lane>>4, n=lane&15;
    int cl=wv*4+grp, pair=p0+cl, c=c0+cl;
    float An=-__expf(A_log[c*16+n]);
    float carry=0.f, sdt=0.f;
    #pragma unroll 8
    for(int l=0;l<CL_;l++){
        float2 dx=dxL[l][cl];
        float bv=bcL[l][n];
        float dA=__expf(dx.x*An);
        carry=fmaf(dA,carry,dx.x*bv*dx.y);
        sdt+=dx.x;
    }
    int idx=(pair*CK_+ck)*16+n;
    Ap[idx]=__expf(An*sdt); Ho[idx]=carry;
}

__global__ __launch_bounds__(256) void k_scan2(
    const float* __restrict__ Ap, const float* __restrict__ Ho, float* __restrict__ Sb)
{
    int gid=blockIdx.x*256+threadIdx.x;
    int pair=gid>>4, n=gid&15;
    float S=0.f;
    #pragma unroll
    for(int ck=0;ck<CK_;ck++){
        int idx=(pair*CK_+ck)*16+n;
        Sb[idx]=S;
        S=fmaf(Ap[idx],S,Ho[idx]);
    }
}

// scan3: replay with carry-in; shuffle-free LDS transpose reduction
__global__ __launch_bounds__(256) void k_scan3(
    const unsigned short* __restrict__ seqb, const float* __restrict__ dtlc,
    const float* __restrict__ BC, const float* __restrict__ A_log,
    const float* __restrict__ Dsk, const float* __restrict__ Sb,
    float* __restrict__ y)
{
    __shared__ float2 dxL[64][17];
    __shared__ float  bcL[64][32];
    __shared__ float  sc[16][16][17];   // [cl][l2][n+pad]; reused as y tile
    int tid=threadIdx.x;
    int blk=blockIdx.x, cg=blk>>6, ck=blk&63;
    int p0=cg*16, b=p0>>8, c0=p0&255;
    int l0=ck*CL_;
    {
        int lr=tid>>2, c4=tid&3;
        size_t base=((size_t)(b*L_+l0+lr))*C_ + c0 + c4*4;
        ushort4 xu=*(const ushort4*)(seqb+base);
        float4 d4=*(const float4*)(dtlc+base);
        dxL[lr][c4*4+0]=make_float2(d4.x,b2f_(xu.x));
        dxL[lr][c4*4+1]=make_float2(d4.y,b2f_(xu.y));
        dxL[lr][c4*4+2]=make_float2(d4.z,b2f_(xu.z));
        dxL[lr][c4*4+3]=make_float2(d4.w,b2f_(xu.w));
        const float* bs=BC+((size_t)(b*L_+l0+lr))*32 + c4*8;
        float4 bv0=*(const float4*)bs, bv1=*(const float4*)(bs+4);
        *(float4*)&bcL[lr][c4*8]=bv0;
        *(float4*)&bcL[lr][c4*8+4]=bv1;
    }
    __syncthreads();
    int wv=tid>>6, lane=tid&63, grp=lane>>4, n=lane&15;
    int cl=wv*4+grp, pair=p0+cl, c=c0+cl;
    float An=-__expf(A_log[c*16+n]);
    float Dc=Dsk[c];
    float carry=Sb[(pair*CK_+ck)*16+n];
    float ybuf[4], xsv[4];
    #pragma unroll
    for(int q=0;q<4;q++){
        float parts[16];
        #pragma unroll
        for(int l2=0;l2<16;l2++){
            int l=q*16+l2;
            float2 dx=dxL[l][cl];
            float bv=bcL[l][n];
            float cv=bcL[l][16+n];
            float dA=__expf(dx.x*An);
            carry=fmaf(dA,carry,dx.x*bv*dx.y);
            parts[l2]=carry*cv;
            if(l2==n) xsv[q]=dx.y;
        }
        #pragma unroll
        for(int l2=0;l2<16;l2++) sc[cl][l2][n]=parts[l2];
        __syncthreads();
        float s=0.f;
        #pragma unroll
        for(int n2=0;n2<16;n2++) s+=sc[cl][n][n2];
        ybuf[q]=fmaf(Dc,xsv[q],s);
        __syncthreads();
    }
    float* yT=(float*)&sc[0][0][0];     // [64][17]
    #pragma unroll
    for(int q=0;q<4;q++){
        int l=q*16+n;
        yT[l*17+cl]=ybuf[q];
    }
    __syncthreads();
    {
        int lr=tid>>2, c4=tid&3;
        size_t base=((size_t)(b*L_+l0+lr))*C_ + c0 + c4*4;
        float4 o=make_float4(yT[lr*17+c4*4+0],yT[lr*17+c4*4+1],
                             yT[lr*17+c4*4+2],yT[lr*17+c4*4+3]);
        *(float4*)(y+base)=o;
    }
}

// ---------------- final LN + transpose out ----------------
__global__ __launch_bounds__(256) void k_final(
    const float* __restrict__ t, const float* __restrict__ pg,
    const float* __restrict__ pb, float* __restrict__ out)
{
    __shared__ float tile[16*257];
    __shared__ float mrs[16][2];
    int blk=blockIdx.x, b=blk>>8, d=(blk>>4)&15, h=blk&15;
    int tid=threadIdx.x;
    for(int w2=0;w2<16;w2++){
        tile[w2*257+tid]=t[((size_t)b*L_+(h*16+w2)*16+d)*C_+tid];
    }
    __syncthreads();
    int r=tid>>4, p=tid&15;
    float s=0.f, ss=0.f;
    #pragma unroll
    for(int k=0;k<16;k++){ float v=tile[r*257+k*16+p]; s+=v; ss+=v*v; }
    #pragma unroll
    for(int m=1;m<16;m<<=1){ s+=__shfl_xor(s,m); ss+=__shfl_xor(ss,m); }
    if(p==0){ float mn=s*(1.f/256.f); mrs[r][0]=mn; mrs[r][1]=rsqrtf(ss*(1.f/256.f)-mn*mn+1e-5f); }
    __syncthreads();
    int w2=tid&15;
    for(int p2=0;p2<16;p2++){
        int c=(tid>>4)+16*p2;
        float v=tile[w2*257+c];
        float vn=(v-mrs[w2][0])*mrs[w2][1]*pg[c]+pb[c];
        out[((size_t)(b*C_+c))*4096 + d*256 + h*16 + w2]=vn;
    }
}

extern "C" void kernel_launch(void* const* d_in, const int* in_sizes, int n_in,
                              void* d_out, int out_size, void* d_ws, size_t ws_size,
                              hipStream_t stream)
{
    (void)in_sizes; (void)n_in; (void)out_size; (void)ws_size;
    const float* x      =(const float*)d_in[0];
    const float* in_w   =(const float*)d_in[1];
    const float* conv_w =(const float*)d_in[2];
    const float* conv_b =(const float*)d_in[3];
    const float* xproj_w=(const float*)d_in[4];
    const float* dt_w   =(const float*)d_in[5];
    const float* dt_b   =(const float*)d_in[6];
    const float* A_log  =(const float*)d_in[7];
    const float* D_skip =(const float*)d_in[8];
    const float* on_g   =(const float*)d_in[9];
    const float* on_b   =(const float*)d_in[10];
    const float* out_w  =(const float*)d_in[11];
    const float* ln1_g  =(const float*)d_in[12];
    const float* ln1_b  =(const float*)d_in[13];
    const float* post_g =(const float*)d_in[14];
    const float* post_b =(const float*)d_in[15];
    float* out=(float*)d_out;
    float* ws=(float*)d_ws;

    const size_t NBL=(size_t)BL_*C_;     // 2,097,152 elems
    float* t    = ws;                     // residual stream [B][L][C]
    float* xs   = ws +   NBL;             // conv input; reused as dtlc after conv
    float* z    = ws + 2*NBL;
    float* seq  = ws + 3*NBL;             // scan3 writes y here (fp32)
    float* BC   = ws + 4*NBL;             // [B*L][32] fp32 (Bm | Cm)
    float* Ap   = BC + (size_t)BL_*32;
    float* Ho   = Ap + 512*CK_*16;
    float* Sb   = Ho + 512*CK_*16;
    unsigned short* seqb = (unsigned short*)(Sb + 512*CK_*16);  // bf16 conv output
    unsigned short* wbI  = seqb + NBL;                          // bf16 in_w  (4*512*256)
    unsigned short* wbO  = wbI + (size_t)DEPTH_*512*C_;         // bf16 out_w (4*256*256)
    unsigned short* xwb  = wbO + (size_t)DEPTH_*C_*C_;          // bf16 xproj_w (4*48*256)
    unsigned short* wdtb = xwb + (size_t)DEPTH_*48*C_;          // bf16 W_eff (4*256*256)
    float* dtlc = xs;                     // dt[l][c] fp32 — aliases xs (dead after conv)

    k_prep<<<1840,256,0,stream>>>(in_w, out_w, xproj_w, dt_w, wbI, wbO, xwb, wdtb);
    k_t_in<<<512,256,0,stream>>>(x,t);
    for(int i=0;i<DEPTH_;i++){
        int ori=i&7;
        k_ln_gemm_in<<<dim3(128,8),256,0,stream>>>(t, ln1_g+i*256, ln1_b+i*256, wbI+(size_t)i*512*C_, xs, z);
        k_conv<<<512,256,0,stream>>>(xs, conv_w+(size_t)i*6912, conv_b+i*256, seqb, ori);
        k_gemm_xdt<<<dim3(128,5),256,0,stream>>>(seqb, xwb+(size_t)i*48*C_, wdtb+(size_t)i*C_*C_, dt_b+i*256, BC, dtlc);
        k_scan1<<<2048,256,0,stream>>>(seqb, dtlc, BC, A_log+(size_t)i*4096, Ap, Ho);
        k_scan2<<<32,256,0,stream>>>(Ap, Ho, Sb);
        k_scan3<<<2048,256,0,stream>>>(seqb, dtlc, BC, A_log+(size_t)i*4096, D_skip+i*256, Sb, seq);
        k_post_gemm_out<<<dim3(128,4),256,0,stream>>>(seq, z, on_g+i*256, on_b+i*256, wbO+(size_t)i*C_*C_, t, ori);
    }
    k_final<<<512,256,0,stream>>>(t, post_g, post_b, out);
}